// Round 4
// baseline (353.092 us; speedup 1.0000x reference)
//
#include <hip/hip_runtime.h>
#include <hip/hip_cooperative_groups.h>
#include <hip/hip_bf16.h>

namespace cg = cooperative_groups;

#define B 16
#define V 1024
#define D 16
#define E 64
#define F 16
#define H 128
#define HD 64
#define BV (B*V)      // 16384
#define BVD (B*V*D)   // 262144

// ---- workspace layout (float offsets) ----
#define OFF_HNB      0                         // hnode layer2 bf16 (BV*H shorts)
#define OFF_NORM     (OFF_HNB + BV*H/2)        // sparsemax output fp32 (BVD)
#define OFF_DV       (OFF_NORM + BVD)          // dual vars (BV)
#define OFF_WT       (OFF_DV + BV)             // 512x256 bf16 GRU weights
#define OFF_WTG      (OFF_WT + 65536)          // 128x128 bf16 GAT weights
#define OFF_WPQ      (OFF_WTG + 8192)          // 128x128 bf16 dec [P|Q] weights
#define OFF_WU1T     (OFF_WPQ + 8192)          // 64x128 bf16 dual W1^T
#define OFF_WENCT    (OFF_WU1T + 4096)         // 128x96 bf16 enc W^T (K padded 80->96)

typedef __attribute__((ext_vector_type(8))) short bf16x8;
typedef __attribute__((ext_vector_type(4))) float f32x4;

__device__ __forceinline__ short f2bf(float f){
  __hip_bfloat16 b = __float2bfloat16(f);
  return *reinterpret_cast<short*>(&b);
}
__device__ __forceinline__ float bf2f(short s){
  __hip_bfloat16 b; *reinterpret_cast<short*>(&b) = s;
  return __bfloat162float(b);
}
__device__ __forceinline__ float frcp(float x){ return __builtin_amdgcn_rcpf(x); }
__device__ __forceinline__ float fsig(float x){ return frcp(1.f + __expf(-x)); }
__device__ __forceinline__ float ftanh(float x){
  float e = __expf(-2.f*fabsf(x));
  float r = (1.f - e)*frcp(1.f + e);
  return copysignf(r, x);
}

// ---- weight packs + output zeroing (runs first in stream) ----
__global__ __launch_bounds__(256) void k_pre(const float* __restrict__ Wx, const float* __restrict__ Wh,
    const float* __restrict__ Wg, const float* __restrict__ W1, const float* __restrict__ Wu1,
    const float* __restrict__ Wenc,
    short* __restrict__ Wt, short* __restrict__ Wgt, short* __restrict__ Wpq,
    short* __restrict__ Wu1t, short* __restrict__ Wenct, float* __restrict__ outz){
  int bid = blockIdx.x, tid = threadIdx.x;
  if (bid == 0 && tid < 16) outz[tid] = 0.f;   // flow segment atomicAdds into this
  if (bid < 512){
    int n = bid, k = tid;
    int g = n >> 7, j = n & 127;
    float v;
    if (g == 0)      v = (k < 128) ? Wx[k*384 + j]       : Wh[(k-128)*384 + j];
    else if (g == 1) v = (k < 128) ? Wx[k*384 + 128 + j] : Wh[(k-128)*384 + 128 + j];
    else if (g == 2) v = (k < 128) ? Wx[k*384 + 256 + j] : 0.f;
    else             v = (k < 128) ? 0.f                 : Wh[(k-128)*384 + 256 + j];
    Wt[n*256 + k] = f2bf(v);
    return;
  }
  if (bid < 576){
    int idx = (bid-512)*256 + tid;
    int n = idx >> 7, k = idx & 127;
    Wgt[n*128 + k] = f2bf(Wg[k*128 + n]);
    return;
  }
  if (bid < 608){
    int idx = (bid-576)*256 + tid;
    int n = idx >> 7, k = idx & 127;
    float wb = W1[(k+128)*HD + n];
    float wa = W1[k*HD + n];
    Wpq[n*128 + k]      = f2bf(wa + wb);
    Wpq[(64+n)*128 + k] = f2bf(wb);
    return;
  }
  if (bid < 640){
    int idx = (bid-608)*256 + tid;
    int n = idx >> 7, k = idx & 127;
    Wu1t[n*128 + k] = f2bf(Wu1[k*HD + n]);
    return;
  }
  {
    int nn = (bid-640)*2 + (tid >> 7);
    int kk = tid & 127;
    if (kk < 96) Wenct[nn*96 + kk] = f2bf(kk < 80 ? Wenc[kk*128 + nn] : 0.f);
  }
}

// FUSED: mega (r3) + decdas (r0 512-thr) + flowfin (halo), one cooperative
// kernel. 256 blocks x 512 threads, 1 block/CU (LDS 114KB) -> all co-resident;
// grid.sync + threadfence between segments replaces 2 kernel boundaries.
__global__ __launch_bounds__(512,2) void k_fused(
    const float* __restrict__ emb, const float* __restrict__ nf,
    const short* __restrict__ Wenct, const float* __restrict__ benc, const int* __restrict__ adj,
    const short* __restrict__ Wgt, const float* __restrict__ bg, const float* __restrict__ ag,
    const short* __restrict__ Wt, const float* __restrict__ bgru, short* __restrict__ hout,
    const int* __restrict__ invadj, const short* __restrict__ Wpq, const float* __restrict__ b1,
    const float* __restrict__ W2, const float* __restrict__ b2_,
    const short* __restrict__ Wu1t, const float* __restrict__ bu1, const float* __restrict__ Wu2,
    const float* __restrict__ bu2_,
    float* __restrict__ norm_, float* __restrict__ dv,
    const float* __restrict__ dem, float* __restrict__ out){
  __shared__ union {
    struct {
      short NE[96][136];
      short Tt[128][104];
      short H1[80][136];
      short X[80][136];
      short A2[80][104];
      float Lp[8][96];
      float Ls[96];
      float nrmv[96];
    } a;
    struct {
      short Hs[112][136];
      short PQb[112][132];
      short NSs[64][136];
      int adjL[64][16];
      float dvp[64][4];
      float b1s[64], w2s[64], bu1s[64], wu2s[64];
    } b;
    struct {
      float nrmS[224*17];
      float sbuf[2][224];
      float red[8];
    } c;
  } U;

  int tid = threadIdx.x;
  int blk = blockIdx.x;
  int b = blk >> 4;
  int n0 = (blk & 15) << 6;
  int w = tid >> 6, lane = tid & 63;
  int l15 = lane & 15, quad = lane >> 4;

  // ================= SEGMENT A: encoder + 2x (GAT + GRU) =================
  {
    auto& NE = U.a.NE; auto& Tt = U.a.Tt; auto& H1 = U.a.H1; auto& X = U.a.X;
    auto& A2 = U.a.A2; auto& Lp = U.a.Lp; auto& Ls = U.a.Ls; auto& nrmv = U.a.nrmv;
    short (*As)[104] = reinterpret_cast<short(*)[104]>(&H1[0][0]);  // enc staging overlay

    // ---- adj prefetch: thread tid<80 owns frame-80 row tid (node n0-8+tid) ----
    int li96[16];
    if (tid < 80){
      int wg = (b<<10) + ((n0 - 8 + tid) & 1023);
      const int4* a4 = reinterpret_cast<const int4*>(&adj[(long)wg*16]);
      #pragma unroll
      for (int d4=0; d4<4; d4++){
        int4 i4 = a4[d4];
        li96[d4*4+0] = (i4.x - n0 + 16) & 1023;
        li96[d4*4+1] = (i4.y - n0 + 16) & 1023;
        li96[d4*4+2] = (i4.z - n0 + 16) & 1023;
        li96[d4*4+3] = (i4.w - n0 + 16) & 1023;
      }
    }

    // ---- E1: emb norms for 96 frame rows; 384 threads, 4 per row ----
    if (tid < 384){
      int r = tid >> 2, q = tid & 3;
      int v = (n0 - 16 + r) & 1023;
      const float4* e4 = reinterpret_cast<const float4*>(&emb[v*E]);
      float ss = 0.f;
      #pragma unroll
      for (int qq=0;qq<4;qq++){ float4 x = e4[q*4+qq]; ss += x.x*x.x + x.y*x.y + x.z*x.z + x.w*x.w; }
      ss += __shfl_xor(ss, 1);
      ss += __shfl_xor(ss, 2);
      if (q == 0) nrmv[r] = frcp(fmaxf(sqrtf(ss), 1.f));
    }
    __syncthreads();
    // ---- E2: stage As[96][96] bf16 ----
    for (int e=tid; e<96*16; e+=512){
      int r = e >> 4, q = e & 15;
      int v = (n0 - 16 + r) & 1023;
      float4 x = reinterpret_cast<const float4*>(&emb[v*E])[q];
      float iv = nrmv[r];
      short4 s; s.x=f2bf(x.x*iv); s.y=f2bf(x.y*iv); s.z=f2bf(x.z*iv); s.w=f2bf(x.w*iv);
      *reinterpret_cast<short4*>(&As[r][q*4]) = s;
    }
    for (int e=tid; e<96*4; e+=512){
      int r = e >> 2, q = e & 3;
      int m = (b<<10) + ((n0 - 16 + r) & 1023);
      float4 x = reinterpret_cast<const float4*>(&nf[(long)m*F])[q];
      short4 s; s.x=f2bf(x.x); s.y=f2bf(x.y); s.z=f2bf(x.z); s.w=f2bf(x.w);
      *reinterpret_cast<short4*>(&As[r][64 + q*4]) = s;
      short4 z; z.x=0; z.y=0; z.z=0; z.w=0;
      *reinterpret_cast<short4*>(&As[r][80 + q*4]) = z;
    }
    __syncthreads();
    // ---- E3: encoder MFMA (96 rows x 128 cols, K=96) ----
    {
      f32x4 acc[6];
      #pragma unroll
      for (int mt=0;mt<6;mt++) acc[mt] = (f32x4){0.f,0.f,0.f,0.f};
      #pragma unroll
      for (int kc=0;kc<3;kc++){
        int k0 = kc*32;
        bf16x8 bfr = *reinterpret_cast<const bf16x8*>(&Wenct[(16*w + l15)*96 + k0 + quad*8]);
        #pragma unroll
        for (int mt=0;mt<6;mt++){
          bf16x8 a = *reinterpret_cast<const bf16x8*>(&As[16*mt + l15][k0 + quad*8]);
          acc[mt] = __builtin_amdgcn_mfma_f32_16x16x32_bf16(a, bfr, acc[mt], 0,0,0);
        }
      }
      int c = 16*w + l15;
      float bb = benc[c];
      #pragma unroll
      for (int mt=0;mt<6;mt++)
        #pragma unroll
        for (int reg=0;reg<4;reg++)
          NE[16*mt + quad*4 + reg][c] = f2bf(acc[mt][reg] + bb);
    }
    __syncthreads();
    // ---- P1: GAT-1 t + logits for 96 rows; writes Tt transposed ----
    {
      f32x4 acc[6];
      #pragma unroll
      for (int mt=0;mt<6;mt++) acc[mt] = (f32x4){0.f,0.f,0.f,0.f};
      #pragma unroll
      for (int kc=0;kc<4;kc++){
        int k0 = kc*32;
        bf16x8 bfr = *reinterpret_cast<const bf16x8*>(&Wgt[(16*w + l15)*128 + k0 + quad*8]);
        #pragma unroll
        for (int mt=0;mt<6;mt++){
          bf16x8 a = *reinterpret_cast<const bf16x8*>(&NE[16*mt + l15][k0 + quad*8]);
          acc[mt] = __builtin_amdgcn_mfma_f32_16x16x32_bf16(a, bfr, acc[mt], 0,0,0);
        }
      }
      int c = 16*w + l15;
      float bgc = bg[c], agc = ag[c];
      float lp[6][4];
      #pragma unroll
      for (int mt=0;mt<6;mt++){
        short4 tv;
        #pragma unroll
        for (int reg=0;reg<4;reg++){
          float t = ftanh(acc[mt][reg] + bgc);
          reinterpret_cast<short*>(&tv)[reg] = f2bf(t);
          lp[mt][reg] = t * agc;
        }
        *reinterpret_cast<short4*>(&Tt[c][16*mt + quad*4]) = tv;
      }
      #pragma unroll
      for (int mt=0;mt<6;mt++)
        #pragma unroll
        for (int reg=0;reg<4;reg++){
          lp[mt][reg] += __shfl_xor(lp[mt][reg], 1);
          lp[mt][reg] += __shfl_xor(lp[mt][reg], 2);
          lp[mt][reg] += __shfl_xor(lp[mt][reg], 4);
          lp[mt][reg] += __shfl_xor(lp[mt][reg], 8);
        }
      if (l15 == 0){
        #pragma unroll
        for (int mt=0;mt<6;mt++)
          #pragma unroll
          for (int reg=0;reg<4;reg++)
            Lp[w][16*mt + quad*4 + reg] = lp[mt][reg];
      }
    }
    __syncthreads();
    // ---- Ls (96 rows) + zero A2[80][0..96) ----
    if (tid < 96){
      float s = 0.f;
      #pragma unroll
      for (int i=0;i<8;i++) s += Lp[i][tid];
      Ls[tid] = s;
    }
    {
      bf16x8 z8;
      #pragma unroll
      for (int q=0;q<8;q++) z8[q] = 0;
      for (int idx=tid; idx<960; idx+=512){
        int r = idx/12, c8 = idx%12;
        *reinterpret_cast<bf16x8*>(&A2[r][c8*8]) = z8;
      }
    }
    __syncthreads();
    // ---- P2a: softmax + scatter into A2 (80 nodes) ----
    if (tid < 80){
      float at[16];
      float m = -1e30f;
      #pragma unroll
      for (int d=0; d<16; d++) m = fmaxf(m, Ls[li96[d]]);
      float s = 0.f;
      #pragma unroll
      for (int d=0; d<16; d++){ at[d] = __expf(Ls[li96[d]] - m); s += at[d]; }
      float inv = frcp(s);
      #pragma unroll
      for (int d=0; d<16; d++) A2[tid][li96[d]] = f2bf(at[d]*inv);
    }
    __syncthreads();
    // ---- P2b: msg1 = A2[80][96] x T[96][128] via MFMA; x1 -> X[0..80) ----
    {
      f32x4 acc[5];
      #pragma unroll
      for (int mt=0;mt<5;mt++) acc[mt] = (f32x4){0.f,0.f,0.f,0.f};
      #pragma unroll
      for (int kc=0;kc<3;kc++){
        int k0 = kc*32;
        bf16x8 bfr = *reinterpret_cast<const bf16x8*>(&Tt[16*w + l15][k0 + quad*8]);
        #pragma unroll
        for (int mt=0;mt<5;mt++){
          bf16x8 a = *reinterpret_cast<const bf16x8*>(&A2[16*mt + l15][k0 + quad*8]);
          acc[mt] = __builtin_amdgcn_mfma_f32_16x16x32_bf16(a, bfr, acc[mt], 0,0,0);
        }
      }
      int c = 16*w + l15;
      #pragma unroll
      for (int mt=0;mt<5;mt++)
        #pragma unroll
        for (int reg=0;reg<4;reg++){
          int rl = 16*mt + quad*4 + reg;
          X[rl][c] = f2bf(ftanh(acc[mt][reg] + bf2f(NE[rl + 8][c])));
        }
    }
    __syncthreads();
    // ---- P3: GRU-1 for 80 rows ----
    {
      f32x4 acc[5][4];
      #pragma unroll
      for (int mt=0;mt<5;mt++)
        #pragma unroll
        for (int g=0;g<4;g++) acc[mt][g] = (f32x4){0.f,0.f,0.f,0.f};
      for (int k8=0;k8<8;k8++){
        int k0 = k8*32;
        int gg = (k8 < 4) ? 2 : 3;
        int ncol = 16*w + l15;
        int koff = k0 + quad*8;
        bf16x8 bz = *reinterpret_cast<const bf16x8*>(&Wt[(ncol      )*256 + koff]);
        bf16x8 br = *reinterpret_cast<const bf16x8*>(&Wt[(ncol + 128)*256 + koff]);
        bf16x8 bc = *reinterpret_cast<const bf16x8*>(&Wt[(ncol + gg*128)*256 + koff]);
        #pragma unroll
        for (int mt=0;mt<5;mt++){
          bf16x8 a;
          if (k8 < 4) a = *reinterpret_cast<const bf16x8*>(&X[16*mt + l15][k0 + quad*8]);
          else        a = *reinterpret_cast<const bf16x8*>(&NE[16*mt + l15 + 8][k0 - 128 + quad*8]);
          acc[mt][0]  = __builtin_amdgcn_mfma_f32_16x16x32_bf16(a, bz, acc[mt][0], 0,0,0);
          acc[mt][1]  = __builtin_amdgcn_mfma_f32_16x16x32_bf16(a, br, acc[mt][1], 0,0,0);
          acc[mt][gg] = __builtin_amdgcn_mfma_f32_16x16x32_bf16(a, bc, acc[mt][gg], 0,0,0);
        }
      }
      int j = 16*w + l15;
      float bjz = bgru[j], bjr = bgru[128 + j], bjc = bgru[256 + j];
      #pragma unroll
      for (int mt=0;mt<5;mt++){
        #pragma unroll
        for (int reg=0;reg<4;reg++){
          int rl = 16*mt + quad*4 + reg;
          float z = fsig(acc[mt][0][reg] + bjz);
          float r = fsig(acc[mt][1][reg] + bjr);
          float cand = ftanh(acc[mt][2][reg] + bjc + r*acc[mt][3][reg]);
          float ho = bf2f(NE[rl + 8][j]);
          H1[rl][j] = f2bf(z*ho + (1.f - z)*cand);
        }
      }
    }
    __syncthreads();
    // ---- P4: GAT-2 t + logits for 80 rows; writes Tt transposed ----
    {
      f32x4 acc[5];
      #pragma unroll
      for (int mt=0;mt<5;mt++) acc[mt] = (f32x4){0.f,0.f,0.f,0.f};
      #pragma unroll
      for (int kc=0;kc<4;kc++){
        int k0 = kc*32;
        bf16x8 bfr = *reinterpret_cast<const bf16x8*>(&Wgt[(16*w + l15)*128 + k0 + quad*8]);
        #pragma unroll
        for (int mt=0;mt<5;mt++){
          bf16x8 a = *reinterpret_cast<const bf16x8*>(&H1[16*mt + l15][k0 + quad*8]);
          acc[mt] = __builtin_amdgcn_mfma_f32_16x16x32_bf16(a, bfr, acc[mt], 0,0,0);
        }
      }
      int c = 16*w + l15;
      float bgc = bg[c], agc = ag[c];
      float lp[5][4];
      #pragma unroll
      for (int mt=0;mt<5;mt++){
        short4 tv;
        #pragma unroll
        for (int reg=0;reg<4;reg++){
          float t = ftanh(acc[mt][reg] + bgc);
          reinterpret_cast<short*>(&tv)[reg] = f2bf(t);
          lp[mt][reg] = t * agc;
        }
        *reinterpret_cast<short4*>(&Tt[c][16*mt + quad*4]) = tv;
      }
      #pragma unroll
      for (int mt=0;mt<5;mt++)
        #pragma unroll
        for (int reg=0;reg<4;reg++){
          lp[mt][reg] += __shfl_xor(lp[mt][reg], 1);
          lp[mt][reg] += __shfl_xor(lp[mt][reg], 2);
          lp[mt][reg] += __shfl_xor(lp[mt][reg], 4);
          lp[mt][reg] += __shfl_xor(lp[mt][reg], 8);
        }
      if (l15 == 0){
        #pragma unroll
        for (int mt=0;mt<5;mt++)
          #pragma unroll
          for (int reg=0;reg<4;reg++)
            Lp[w][16*mt + quad*4 + reg] = lp[mt][reg];
      }
    }
    __syncthreads();
    // ---- Ls (80 rows) + zero A2[64][0..96) ----
    if (tid < 80){
      float s = 0.f;
      #pragma unroll
      for (int i=0;i<8;i++) s += Lp[i][tid];
      Ls[tid] = s;
    }
    {
      bf16x8 z8;
      #pragma unroll
      for (int q=0;q<8;q++) z8[q] = 0;
      for (int idx=tid; idx<768; idx+=512){
        int r = idx/12, c8 = idx%12;
        *reinterpret_cast<bf16x8*>(&A2[r][c8*8]) = z8;
      }
    }
    __syncthreads();
    // ---- P5a: softmax + scatter into A2 (64 owned) ----
    if (tid >= 8 && tid < 72){
      int r5 = tid - 8;
      float at[16];
      float m = -1e30f;
      #pragma unroll
      for (int d=0; d<16; d++) m = fmaxf(m, Ls[li96[d] - 8]);
      float s = 0.f;
      #pragma unroll
      for (int d=0; d<16; d++){ at[d] = __expf(Ls[li96[d] - 8] - m); s += at[d]; }
      float inv = frcp(s);
      #pragma unroll
      for (int d=0; d<16; d++) A2[r5][li96[d] - 8] = f2bf(at[d]*inv);
    }
    __syncthreads();
    // ---- P5b: msg2 = A2[64][80] x T[80][128] via MFMA; x2 -> X[0..64) ----
    {
      f32x4 acc[4];
      #pragma unroll
      for (int mt=0;mt<4;mt++) acc[mt] = (f32x4){0.f,0.f,0.f,0.f};
      #pragma unroll
      for (int kc=0;kc<3;kc++){      // K padded to 96: A2 cols [80,96) are zero
        int k0 = kc*32;
        bf16x8 bfr = *reinterpret_cast<const bf16x8*>(&Tt[16*w + l15][k0 + quad*8]);
        #pragma unroll
        for (int mt=0;mt<4;mt++){
          bf16x8 a = *reinterpret_cast<const bf16x8*>(&A2[16*mt + l15][k0 + quad*8]);
          acc[mt] = __builtin_amdgcn_mfma_f32_16x16x32_bf16(a, bfr, acc[mt], 0,0,0);
        }
      }
      int c = 16*w + l15;
      #pragma unroll
      for (int mt=0;mt<4;mt++)
        #pragma unroll
        for (int reg=0;reg<4;reg++){
          int rl = 16*mt + quad*4 + reg;
          X[rl][c] = f2bf(ftanh(acc[mt][reg] + bf2f(NE[rl + 16][c])));
        }
    }
    __syncthreads();
    // ---- P6: GRU-2 for 64 owned ----
    {
      f32x4 acc[4][4];
      #pragma unroll
      for (int mt=0;mt<4;mt++)
        #pragma unroll
        for (int g=0;g<4;g++) acc[mt][g] = (f32x4){0.f,0.f,0.f,0.f};
      for (int k8=0;k8<8;k8++){
        int k0 = k8*32;
        int gg = (k8 < 4) ? 2 : 3;
        int ncol = 16*w + l15;
        int koff = k0 + quad*8;
        bf16x8 bz = *reinterpret_cast<const bf16x8*>(&Wt[(ncol      )*256 + koff]);
        bf16x8 br = *reinterpret_cast<const bf16x8*>(&Wt[(ncol + 128)*256 + koff]);
        bf16x8 bc = *reinterpret_cast<const bf16x8*>(&Wt[(ncol + gg*128)*256 + koff]);
        #pragma unroll
        for (int mt=0;mt<4;mt++){
          bf16x8 a;
          if (k8 < 4) a = *reinterpret_cast<const bf16x8*>(&X[16*mt + l15][k0 + quad*8]);
          else        a = *reinterpret_cast<const bf16x8*>(&H1[16*mt + l15 + 8][k0 - 128 + quad*8]);
          acc[mt][0]  = __builtin_amdgcn_mfma_f32_16x16x32_bf16(a, bz, acc[mt][0], 0,0,0);
          acc[mt][1]  = __builtin_amdgcn_mfma_f32_16x16x32_bf16(a, br, acc[mt][1], 0,0,0);
          acc[mt][gg] = __builtin_amdgcn_mfma_f32_16x16x32_bf16(a, bc, acc[mt][gg], 0,0,0);
        }
      }
      __syncthreads();   // X is MFMA input above, epilogue output below
      int j = 16*w + l15;
      float bjz = bgru[j], bjr = bgru[128 + j], bjc = bgru[256 + j];
      #pragma unroll
      for (int mt=0;mt<4;mt++){
        #pragma unroll
        for (int reg=0;reg<4;reg++){
          int rl = 16*mt + quad*4 + reg;
          float z = fsig(acc[mt][0][reg] + bjz);
          float r = fsig(acc[mt][1][reg] + bjr);
          float cand = ftanh(acc[mt][2][reg] + bjc + r*acc[mt][3][reg]);
          float ho = bf2f(H1[rl + 8][j]);
          X[rl][j] = f2bf(z*ho + (1.f - z)*cand);
        }
      }
    }
    __syncthreads();
    for (int idx=tid; idx<64*16; idx+=512){
      int r = idx >> 4, c8 = idx & 15;
      *reinterpret_cast<bf16x8*>(&hout[(long)((b<<10) + n0 + r)*128 + c8*8]) =
          *reinterpret_cast<const bf16x8*>(&X[r][c8*8]);
    }
  }

  __threadfence();
  cg::this_grid().sync();

  // ================= SEGMENT B: decoder + dest-attn + sparsemax + dual =================
  {
    auto& Hs = U.b.Hs; auto& PQb = U.b.PQb; auto& NSs = U.b.NSs;
    auto& adjL = U.b.adjL; auto& dvp = U.b.dvp;
    float* b1s = U.b.b1s; float* w2s = U.b.w2s; float* bu1s = U.b.bu1s; float* wu2s = U.b.wu2s;

    if (tid < 64){ b1s[tid] = b1[tid]; w2s[tid] = W2[tid]; bu1s[tid] = bu1[tid]; wu2s[tid] = Wu2[tid]; }
    for (int idx=tid; idx<112*16; idx+=512){
      int r = idx >> 4, c8 = idx & 15;
      int g = (b << 10) + ((n0 - 24 + r) & 1023);
      *reinterpret_cast<bf16x8*>(&Hs[r][c8*8]) =
          *reinterpret_cast<const bf16x8*>(&hout[(long)g*128 + c8*8]);
    }
    for (int idx=tid; idx<1024; idx+=512){
      int r = idx >> 4, d = idx & 15;
      int a = adj[((b<<10) + n0 + r)*16 + d];
      adjL[r][d] = (a - n0 + 24) & 1023;
    }
    __syncthreads();
    // ---- PQ GEMM: wave w owns cols 16w..16w+16 ----
    {
      f32x4 acc[7];
      #pragma unroll
      for (int mt=0;mt<7;mt++) acc[mt] = (f32x4){0.f,0.f,0.f,0.f};
      #pragma unroll
      for (int kc=0;kc<4;kc++){
        int k0 = kc*32;
        bf16x8 bfr = *reinterpret_cast<const bf16x8*>(&Wpq[(16*w + l15)*128 + k0 + quad*8]);
        #pragma unroll
        for (int mt=0;mt<7;mt++){
          bf16x8 a = *reinterpret_cast<const bf16x8*>(&Hs[16*mt + l15][k0 + quad*8]);
          acc[mt] = __builtin_amdgcn_mfma_f32_16x16x32_bf16(a, bfr, acc[mt], 0,0,0);
        }
      }
      int c = 16*w + l15;
      #pragma unroll
      for (int mt=0;mt<7;mt++)
        #pragma unroll
        for (int reg=0;reg<4;reg++)
          PQb[16*mt + quad*4 + reg][c] = f2bf(acc[mt][reg]);
    }
    // ---- node_states gather ----
    for (int idx=tid; idx<64*16; idx+=512){
      int r = idx >> 4, c8 = idx & 15;
      float acc8[8] = {0,0,0,0,0,0,0,0};
      #pragma unroll 4
      for (int d=0; d<16; d++){
        bf16x8 hv = *reinterpret_cast<const bf16x8*>(&Hs[adjL[r][d]][c8*8]);
        #pragma unroll
        for (int q=0;q<8;q++) acc8[q] += bf2f(hv[q]);
      }
      bf16x8 sv;
      #pragma unroll
      for (int q=0;q<8;q++) sv[q] = f2bf(acc8[q]);
      *reinterpret_cast<bf16x8*>(&NSs[r][c8*8]) = sv;
    }
    __syncthreads();
    // ---- dual MLP MFMA on waves 0-3 ----
    if (w < 4){
      f32x4 acc[4];
      #pragma unroll
      for (int mt=0;mt<4;mt++) acc[mt] = (f32x4){0.f,0.f,0.f,0.f};
      #pragma unroll
      for (int kc=0;kc<4;kc++){
        int k0 = kc*32;
        bf16x8 bfr = *reinterpret_cast<const bf16x8*>(&Wu1t[(16*w + l15)*128 + k0 + quad*8]);
        #pragma unroll
        for (int mt=0;mt<4;mt++){
          bf16x8 a = *reinterpret_cast<const bf16x8*>(&NSs[16*mt + l15][k0 + quad*8]);
          acc[mt] = __builtin_amdgcn_mfma_f32_16x16x32_bf16(a, bfr, acc[mt], 0,0,0);
        }
      }
      int n = 16*w + l15;
      float bn = bu1s[n], wn = wu2s[n];
      #pragma unroll
      for (int mt=0;mt<4;mt++){
        #pragma unroll
        for (int reg=0;reg<4;reg++){
          float p = ftanh(acc[mt][reg] + bn) * wn;
          p += __shfl_xor(p, 1);
          p += __shfl_xor(p, 2);
          p += __shfl_xor(p, 4);
          p += __shfl_xor(p, 8);
          if (l15 == 0) dvp[16*mt + quad*4 + reg][w] = p;
        }
      }
    }
    __syncthreads();
    float* nws = reinterpret_cast<float*>(&Hs[0][0]);   // [96][17]
    float b2v = b2_[0];
    for (int e = tid; e < 96*16; e += 512){
      int rr = e >> 4, d = e & 15;
      int wnode = (n0 + rr - 16) & 1023;
      int wg = (b<<10) + wnode;
      int a = adj[wg*16 + d];
      int al = (a - n0 + 24) & 1023;
      int wl = rr + 8;
      float p = 0.f;
      #pragma unroll 8
      for (int c=0;c<64;c++)
        p += ftanh(bf2f(PQb[al][c]) + bf2f(PQb[wl][64 + c]) + b1s[c]) * w2s[c];
      nws[rr*17 + d] = p + b2v;
    }
    __syncthreads();
    if (tid < 64){
      float val = dvp[tid][0]+dvp[tid][1]+dvp[tid][2]+dvp[tid][3];
      dv[(b<<10) + n0 + tid] = fmaxf(val + bu2_[0], 0.f);
    }
    float* datt = reinterpret_cast<float*>(&PQb[0][0]); // [80][17]
    if (tid < 80){
      int wnode = (n0 + tid - 8) & 1023;
      int wg = (b<<10) + wnode;
      float vals[16];
      float m = -1e30f;
      #pragma unroll
      for (int d=0; d<16; d++){
        int iv = invadj[wg*16 + d];
        int il = (iv - n0 + 16) & 1023;
        vals[d] = nws[il*17 + d];
        m = fmaxf(m, vals[d]);
      }
      float s = 0.f;
      #pragma unroll
      for (int d=0; d<16; d++){ vals[d] = __expf(vals[d]-m); s += vals[d]; }
      float inv = frcp(s);
      #pragma unroll
      for (int d=0; d<16; d++) datt[tid*17 + d] = vals[d]*inv;
    }
    __syncthreads();
    if (tid < 64){
      int vg = (b<<10) + n0 + tid;
      float z[16], s[16];
      #pragma unroll
      for (int d=0; d<16; d++){
        int al = adjL[tid][d] - 16;
        z[d] = datt[al*17 + d];
        s[d] = z[d];
      }
      #pragma unroll
      for (int k2 = 2; k2 <= 16; k2 <<= 1){
        #pragma unroll
        for (int jj = k2 >> 1; jj > 0; jj >>= 1){
          #pragma unroll
          for (int i = 0; i < 16; i++){
            int l = i ^ jj;
            if (l > i){
              bool up = ((i & k2) == 0);
              float a = s[i], bb = s[l];
              bool sw = up ? (a > bb) : (a < bb);
              if (sw){ s[i]=bb; s[l]=a; }
            }
          }
        }
      }
      float cs = 0.f, zcs = 0.f; int kz = 1;
      #pragma unroll
      for (int j=0;j<16;j++){
        float zj = s[15-j];
        cs += zj;
        if (1.f + (float)(j+1)*zj > cs){ kz = j+1; zcs = cs; }
      }
      float tau = (zcs - 1.f)/(float)kz;
      #pragma unroll
      for (int d=0; d<16; d++) norm_[(long)vg*16 + d] = fmaxf(z[d]-tau, 0.f);
    }
  }

  __threadfence();
  cg::this_grid().sync();

  // ================= SEGMENT C: flow solver + final reduce =================
  {
    float* nrmS = U.c.nrmS;
    auto& sbuf = U.c.sbuf;
    float* red = U.c.red;
    int t0 = n0;
    for (int e=tid; e<224*4; e+=512){
      int r = e >> 2, q4 = e & 3;
      int v = (t0 - 80 + r) & 1023;
      float4 x = reinterpret_cast<const float4*>(&norm_[(long)((b<<10) + v)*16])[q4];
      nrmS[r*17 + q4*4+0] = x.x; nrmS[r*17 + q4*4+1] = x.y;
      nrmS[r*17 + q4*4+2] = x.z; nrmS[r*17 + q4*4+3] = x.w;
    }
    bool act = tid < 224;
    int r = tid;
    float dm = 0.f; int gv = 0;
    int ivl[16];
    if (act){
      int v = (t0 - 80 + r) & 1023;
      gv = (b<<10) + v;
      dm = dem[gv];
      #pragma unroll
      for (int d4=0; d4<4; d4++){
        int4 i4 = reinterpret_cast<const int4*>(&invadj[(long)gv*16])[d4];
        int t;
        t = (i4.x - t0 + 80) & 1023; ivl[d4*4+0] = t < 224 ? t : 223;
        t = (i4.y - t0 + 80) & 1023; ivl[d4*4+1] = t < 224 ? t : 223;
        t = (i4.z - t0 + 80) & 1023; ivl[d4*4+2] = t < 224 ? t : 223;
        t = (i4.w - t0 + 80) & 1023; ivl[d4*4+3] = t < 224 ? t : 223;
      }
      sbuf[0][r] = 0.f;
    }
    __syncthreads();
    float nrg[16];
    if (act){
      #pragma unroll
      for (int d=0; d<16; d++) nrg[d] = nrmS[ivl[d]*17 + d];
    }
    int p = 0;
    float s = 0.f;
    for (int it=0; it<10; it++){
      if (act){
        float inflow = 0.f;
        #pragma unroll
        for (int d=0; d<16; d++) inflow += nrg[d]*sbuf[p][ivl[d]];
        s = fmaxf(inflow - dm, 0.f);
        sbuf[1-p][r] = s;
      }
      p ^= 1;
      __syncthreads();
    }
    float partF = 0.f, partD = 0.f, partDD = 0.f;
    if (act && r >= 80 && r < 144){
      float nr2 = 0.f;
      #pragma unroll
      for (int d=0; d<16; d++){ float nv = nrmS[r*17 + d]; nr2 += nv*nv; }
      partF = nr2 * s * s;
      float dvv = dv[gv];
      float f = 0.f, vel = 0.f;
      #pragma unroll
      for (int it=0; it<10; it++){
        float g = 2.f*f + dvv;
        vel = 0.9f*vel - 0.01f*g;
        f = fmaxf(f + vel, 0.f);
      }
      partD = f*f + dvv*f;
      partDD = dvv * dm;
    }
    float val = partF - 16.f*partD + partDD;   // out[b] = sum F - (16*sum D - sum DD)
    #pragma unroll
    for (int off=32; off>0; off>>=1) val += __shfl_down(val, off);
    if ((tid & 63) == 0) red[tid>>6] = val;
    __syncthreads();
    if (tid == 0){
      float acc = 0.f;
      #pragma unroll
      for (int i=0;i<8;i++) acc += red[i];
      atomicAdd(&out[b], acc);
    }
  }
}

extern "C" void kernel_launch(void* const* d_in, const int* in_sizes, int n_in,
                              void* d_out, int out_size, void* d_ws, size_t ws_size,
                              hipStream_t stream){
  (void)in_sizes; (void)n_in; (void)out_size; (void)ws_size;
  const float* demands = (const float*)d_in[0];
  const float* nf      = (const float*)d_in[1];
  const float* emb     = (const float*)d_in[4];
  const float* Wenc    = (const float*)d_in[5];
  const float* benc    = (const float*)d_in[6];
  const float* Wgat    = (const float*)d_in[7];
  const float* bgat    = (const float*)d_in[8];
  const float* agat    = (const float*)d_in[9];
  const float* Wgx     = (const float*)d_in[10];
  const float* Wgh     = (const float*)d_in[11];
  const float* bgru    = (const float*)d_in[12];
  const float* Wd1     = (const float*)d_in[13];
  const float* bd1     = (const float*)d_in[14];
  const float* Wd2     = (const float*)d_in[15];
  const float* bd2     = (const float*)d_in[16];
  const float* Wu1     = (const float*)d_in[17];
  const float* bu1     = (const float*)d_in[18];
  const float* Wu2     = (const float*)d_in[19];
  const float* bu2     = (const float*)d_in[20];
  const int* adj       = (const int*)d_in[21];
  const int* invadj    = (const int*)d_in[22];

  float* ws    = (float*)d_ws;
  short* hnB   = (short*)(ws + OFF_HNB);
  float* nrm   = ws + OFF_NORM;
  float* dv    = ws + OFF_DV;
  short* wt    = (short*)(ws + OFF_WT);
  short* wtg   = (short*)(ws + OFF_WTG);
  short* wpq   = (short*)(ws + OFF_WPQ);
  short* wu1t  = (short*)(ws + OFF_WU1T);
  short* wenct = (short*)(ws + OFF_WENCT);
  float* outp  = (float*)d_out;

  k_pre<<<704, 256, 0, stream>>>(Wgx, Wgh, Wgat, Wd1, Wu1, Wenc, wt, wtg, wpq, wu1t, wenct, outp);

  void* kargs[] = {
    (void*)&emb, (void*)&nf, (void*)&wenct, (void*)&benc, (void*)&adj,
    (void*)&wtg, (void*)&bgat, (void*)&agat, (void*)&wt, (void*)&bgru, (void*)&hnB,
    (void*)&invadj, (void*)&wpq, (void*)&bd1, (void*)&Wd2, (void*)&bd2,
    (void*)&wu1t, (void*)&bu1, (void*)&Wu2, (void*)&bu2,
    (void*)&nrm, (void*)&dv, (void*)&demands, (void*)&outp
  };
  hipLaunchCooperativeKernel((const void*)k_fused, dim3(256), dim3(512), kargs, 0, stream);
}

// Round 5
// 186.328 us; speedup vs baseline: 1.8950x; 1.8950x over previous
//
#include <hip/hip_runtime.h>
#include <hip/hip_bf16.h>

#define B 16
#define V 1024
#define D 16
#define E 64
#define F 16
#define H 128
#define HD 64
#define BV (B*V)      // 16384
#define BVD (B*V*D)   // 262144

// ---- workspace layout (float offsets) ----
#define OFF_HNB      0                         // hnode layer2 bf16 (BV*H shorts)
#define OFF_NORM     (OFF_HNB + BV*H/2)        // sparsemax output fp32 (BVD)
#define OFF_DV       (OFF_NORM + BVD)          // dual vars (BV)
#define OFF_WT       (OFF_DV + BV)             // 512x256 bf16 GRU weights
#define OFF_WTG      (OFF_WT + 65536)          // 128x128 bf16 GAT weights
#define OFF_WPQ      (OFF_WTG + 8192)          // 128x128 bf16 dec [P|Q] weights
#define OFF_WU1T     (OFF_WPQ + 8192)          // 64x128 bf16 dual W1^T
#define OFF_WENCT    (OFF_WU1T + 4096)         // 128x96 bf16 enc W^T (K padded 80->96)

typedef __attribute__((ext_vector_type(8))) short bf16x8;
typedef __attribute__((ext_vector_type(4))) float f32x4;

__device__ __forceinline__ short f2bf(float f){
  __hip_bfloat16 b = __float2bfloat16(f);
  return *reinterpret_cast<short*>(&b);
}
__device__ __forceinline__ float bf2f(short s){
  __hip_bfloat16 b; *reinterpret_cast<short*>(&b) = s;
  return __bfloat162float(b);
}
__device__ __forceinline__ float frcp(float x){ return __builtin_amdgcn_rcpf(x); }
__device__ __forceinline__ float fsig(float x){ return frcp(1.f + __expf(-x)); }
__device__ __forceinline__ float ftanh(float x){
  float e = __expf(-2.f*fabsf(x));
  float r = (1.f - e)*frcp(1.f + e);
  return copysignf(r, x);
}

// ---- weight packs + output zeroing (runs first in stream) ----
__global__ __launch_bounds__(256) void k_pre(const float* __restrict__ Wx, const float* __restrict__ Wh,
    const float* __restrict__ Wg, const float* __restrict__ W1, const float* __restrict__ Wu1,
    const float* __restrict__ Wenc,
    short* __restrict__ Wt, short* __restrict__ Wgt, short* __restrict__ Wpq,
    short* __restrict__ Wu1t, short* __restrict__ Wenct, float* __restrict__ outz){
  int bid = blockIdx.x, tid = threadIdx.x;
  if (bid == 0 && tid < 16) outz[tid] = 0.f;   // k_flowfin atomicAdds into this
  if (bid < 512){
    int n = bid, k = tid;
    int g = n >> 7, j = n & 127;
    float v;
    if (g == 0)      v = (k < 128) ? Wx[k*384 + j]       : Wh[(k-128)*384 + j];
    else if (g == 1) v = (k < 128) ? Wx[k*384 + 128 + j] : Wh[(k-128)*384 + 128 + j];
    else if (g == 2) v = (k < 128) ? Wx[k*384 + 256 + j] : 0.f;
    else             v = (k < 128) ? 0.f                 : Wh[(k-128)*384 + 256 + j];
    Wt[n*256 + k] = f2bf(v);
    return;
  }
  if (bid < 576){
    int idx = (bid-512)*256 + tid;
    int n = idx >> 7, k = idx & 127;
    Wgt[n*128 + k] = f2bf(Wg[k*128 + n]);
    return;
  }
  if (bid < 608){
    int idx = (bid-576)*256 + tid;
    int n = idx >> 7, k = idx & 127;
    float wb = W1[(k+128)*HD + n];
    float wa = W1[k*HD + n];
    Wpq[n*128 + k]      = f2bf(wa + wb);
    Wpq[(64+n)*128 + k] = f2bf(wb);
    return;
  }
  if (bid < 640){
    int idx = (bid-608)*256 + tid;
    int n = idx >> 7, k = idx & 127;
    Wu1t[n*128 + k] = f2bf(Wu1[k*HD + n]);
    return;
  }
  {
    int nn = (bid-640)*2 + (tid >> 7);
    int kk = tid & 127;
    if (kk < 96) Wenct[nn*96 + kk] = f2bf(kk < 80 ? Wenc[kk*128 + nn] : 0.f);
  }
}

// MEGA: r3 phase structure (96-frame / 64-owned, MFMA-ized msg, Tt transposed,
// adj prefetch) at 1024 threads / 16 waves. Row-tiles split across wave halves
// (hw = w>>3); plain __launch_bounds__(1024) -> 128-VGPR cap (regsPerBlock),
// per-wave acc arrays are half of r3's 512-thr version so no spill (r2's
// failure was the (1024,4) 56-VGPR squeeze -> 50MB scratch traffic).
__global__ __launch_bounds__(1024) void k_mega(const float* __restrict__ emb, const float* __restrict__ nf,
    const short* __restrict__ Wenct, const float* __restrict__ benc, const int* __restrict__ adj,
    const short* __restrict__ Wgt, const float* __restrict__ bg, const float* __restrict__ ag,
    const short* __restrict__ Wt, const float* __restrict__ bgru, short* __restrict__ hout){
  __shared__ short NE[96][136];
  __shared__ short Tt[128][104];   // transposed GAT t: Tt[col c][frame row j]
  __shared__ short H1[80][136];
  __shared__ short X[80][136];
  __shared__ short A2[80][104];    // sparse attention matrix (bf16)
  __shared__ float Lp[8][96];
  __shared__ float Ls[96];
  __shared__ float nrmv[96];
  short (*As)[104] = reinterpret_cast<short(*)[104]>(&H1[0][0]);  // enc staging overlay

  int tid = threadIdx.x;
  int blk = blockIdx.x;
  int b = blk >> 4;
  int n0 = (blk & 15) << 6;
  int w = tid >> 6, lane = tid & 63;
  int l15 = lane & 15, quad = lane >> 4;
  int cw = w & 7, hw = w >> 3;     // column-wave 0..7, row-half 0..1

  // ---- adj prefetch: thread tid<80 owns frame-80 row tid (node n0-8+tid) ----
  int li96[16];
  if (tid < 80){
    int wg = (b<<10) + ((n0 - 8 + tid) & 1023);
    const int4* a4 = reinterpret_cast<const int4*>(&adj[(long)wg*16]);
    #pragma unroll
    for (int d4=0; d4<4; d4++){
      int4 i4 = a4[d4];
      li96[d4*4+0] = (i4.x - n0 + 16) & 1023;
      li96[d4*4+1] = (i4.y - n0 + 16) & 1023;
      li96[d4*4+2] = (i4.z - n0 + 16) & 1023;
      li96[d4*4+3] = (i4.w - n0 + 16) & 1023;
    }
  }

  // ---- E1: emb norms for 96 frame rows; 384 threads, 4 per row ----
  if (tid < 384){
    int r = tid >> 2, q = tid & 3;
    int v = (n0 - 16 + r) & 1023;
    const float4* e4 = reinterpret_cast<const float4*>(&emb[v*E]);
    float ss = 0.f;
    #pragma unroll
    for (int qq=0;qq<4;qq++){ float4 x = e4[q*4+qq]; ss += x.x*x.x + x.y*x.y + x.z*x.z + x.w*x.w; }
    ss += __shfl_xor(ss, 1);
    ss += __shfl_xor(ss, 2);
    if (q == 0) nrmv[r] = frcp(fmaxf(sqrtf(ss), 1.f));
  }
  __syncthreads();
  // ---- E2: stage As[96][96] bf16 ----
  for (int e=tid; e<96*16; e+=1024){
    int r = e >> 4, q = e & 15;
    int v = (n0 - 16 + r) & 1023;
    float4 x = reinterpret_cast<const float4*>(&emb[v*E])[q];
    float iv = nrmv[r];
    short4 s; s.x=f2bf(x.x*iv); s.y=f2bf(x.y*iv); s.z=f2bf(x.z*iv); s.w=f2bf(x.w*iv);
    *reinterpret_cast<short4*>(&As[r][q*4]) = s;
  }
  for (int e=tid; e<96*4; e+=1024){
    int r = e >> 2, q = e & 3;
    int m = (b<<10) + ((n0 - 16 + r) & 1023);
    float4 x = reinterpret_cast<const float4*>(&nf[(long)m*F])[q];
    short4 s; s.x=f2bf(x.x); s.y=f2bf(x.y); s.z=f2bf(x.z); s.w=f2bf(x.w);
    *reinterpret_cast<short4*>(&As[r][64 + q*4]) = s;
    short4 z; z.x=0; z.y=0; z.z=0; z.w=0;
    *reinterpret_cast<short4*>(&As[r][80 + q*4]) = z;
  }
  __syncthreads();
  // ---- E3: encoder MFMA (96 rows x 128 cols, K=96); 6 tiles = 3 per half ----
  {
    f32x4 acc[3];
    #pragma unroll
    for (int t=0;t<3;t++) acc[t] = (f32x4){0.f,0.f,0.f,0.f};
    #pragma unroll
    for (int kc=0;kc<3;kc++){
      int k0 = kc*32;
      bf16x8 bfr = *reinterpret_cast<const bf16x8*>(&Wenct[(16*cw + l15)*96 + k0 + quad*8]);
      #pragma unroll
      for (int t=0;t<3;t++){
        bf16x8 a = *reinterpret_cast<const bf16x8*>(&As[16*(3*hw+t) + l15][k0 + quad*8]);
        acc[t] = __builtin_amdgcn_mfma_f32_16x16x32_bf16(a, bfr, acc[t], 0,0,0);
      }
    }
    int c = 16*cw + l15;
    float bb = benc[c];
    #pragma unroll
    for (int t=0;t<3;t++)
      #pragma unroll
      for (int reg=0;reg<4;reg++)
        NE[16*(3*hw+t) + quad*4 + reg][c] = f2bf(acc[t][reg] + bb);
  }
  __syncthreads();
  // ---- P1: GAT-1 t + logits for 96 rows; 3 tiles/half; writes Tt transposed ----
  {
    f32x4 acc[3];
    #pragma unroll
    for (int t=0;t<3;t++) acc[t] = (f32x4){0.f,0.f,0.f,0.f};
    #pragma unroll
    for (int kc=0;kc<4;kc++){
      int k0 = kc*32;
      bf16x8 bfr = *reinterpret_cast<const bf16x8*>(&Wgt[(16*cw + l15)*128 + k0 + quad*8]);
      #pragma unroll
      for (int t=0;t<3;t++){
        bf16x8 a = *reinterpret_cast<const bf16x8*>(&NE[16*(3*hw+t) + l15][k0 + quad*8]);
        acc[t] = __builtin_amdgcn_mfma_f32_16x16x32_bf16(a, bfr, acc[t], 0,0,0);
      }
    }
    int c = 16*cw + l15;
    float bgc = bg[c], agc = ag[c];
    float lp[3][4];
    #pragma unroll
    for (int t=0;t<3;t++){
      short4 tv;
      #pragma unroll
      for (int reg=0;reg<4;reg++){
        float tt = ftanh(acc[t][reg] + bgc);
        reinterpret_cast<short*>(&tv)[reg] = f2bf(tt);
        lp[t][reg] = tt * agc;
      }
      *reinterpret_cast<short4*>(&Tt[c][16*(3*hw+t) + quad*4]) = tv;
    }
    #pragma unroll
    for (int t=0;t<3;t++)
      #pragma unroll
      for (int reg=0;reg<4;reg++){
        lp[t][reg] += __shfl_xor(lp[t][reg], 1);
        lp[t][reg] += __shfl_xor(lp[t][reg], 2);
        lp[t][reg] += __shfl_xor(lp[t][reg], 4);
        lp[t][reg] += __shfl_xor(lp[t][reg], 8);
      }
    if (l15 == 0){
      #pragma unroll
      for (int t=0;t<3;t++)
        #pragma unroll
        for (int reg=0;reg<4;reg++)
          Lp[cw][16*(3*hw+t) + quad*4 + reg] = lp[t][reg];
    }
  }
  __syncthreads();
  // ---- Ls (96 rows) + zero A2[80][0..96) ----
  if (tid < 96){
    float s = 0.f;
    #pragma unroll
    for (int i=0;i<8;i++) s += Lp[i][tid];
    Ls[tid] = s;
  }
  if (tid < 960){
    bf16x8 z8;
    #pragma unroll
    for (int q=0;q<8;q++) z8[q] = 0;
    int r = tid/12, c8 = tid%12;
    *reinterpret_cast<bf16x8*>(&A2[r][c8*8]) = z8;
  }
  __syncthreads();
  // ---- P2a: softmax + scatter into A2 (80 nodes) ----
  if (tid < 80){
    float at[16];
    float m = -1e30f;
    #pragma unroll
    for (int d=0; d<16; d++) m = fmaxf(m, Ls[li96[d]]);
    float s = 0.f;
    #pragma unroll
    for (int d=0; d<16; d++){ at[d] = __expf(Ls[li96[d]] - m); s += at[d]; }
    float inv = frcp(s);
    #pragma unroll
    for (int d=0; d<16; d++) A2[tid][li96[d]] = f2bf(at[d]*inv);
  }
  __syncthreads();
  // ---- P2b: msg1 = A2[80][96] x T[96][128] via MFMA; 5 tiles (3+2) ----
  {
    f32x4 acc[3];
    #pragma unroll
    for (int t=0;t<3;t++) acc[t] = (f32x4){0.f,0.f,0.f,0.f};
    #pragma unroll
    for (int kc=0;kc<3;kc++){
      int k0 = kc*32;
      bf16x8 bfr = *reinterpret_cast<const bf16x8*>(&Tt[16*cw + l15][k0 + quad*8]);
      #pragma unroll
      for (int t=0;t<3;t++){
        int mt = 3*hw + t;
        if (mt < 5){
          bf16x8 a = *reinterpret_cast<const bf16x8*>(&A2[16*mt + l15][k0 + quad*8]);
          acc[t] = __builtin_amdgcn_mfma_f32_16x16x32_bf16(a, bfr, acc[t], 0,0,0);
        }
      }
    }
    int c = 16*cw + l15;
    #pragma unroll
    for (int t=0;t<3;t++){
      int mt = 3*hw + t;
      if (mt < 5){
        #pragma unroll
        for (int reg=0;reg<4;reg++){
          int rl = 16*mt + quad*4 + reg;
          X[rl][c] = f2bf(ftanh(acc[t][reg] + bf2f(NE[rl + 8][c])));
        }
      }
    }
  }
  __syncthreads();
  // ---- P3: GRU-1 for 80 rows; hw0 tiles {0,1,2}, hw1 {3,4} ----
  {
    f32x4 acc[3][4];
    #pragma unroll
    for (int t=0;t<3;t++)
      #pragma unroll
      for (int g=0;g<4;g++) acc[t][g] = (f32x4){0.f,0.f,0.f,0.f};
    int ncol = 16*cw + l15;
    for (int k8=0;k8<4;k8++){          // x half: K rows 0..128, cand gate -> acc[.][2]
      int k0 = k8*32;
      int koff = k0 + quad*8;
      bf16x8 bz = *reinterpret_cast<const bf16x8*>(&Wt[(ncol      )*256 + koff]);
      bf16x8 br = *reinterpret_cast<const bf16x8*>(&Wt[(ncol + 128)*256 + koff]);
      bf16x8 bc = *reinterpret_cast<const bf16x8*>(&Wt[(ncol + 256)*256 + koff]);
      #pragma unroll
      for (int t=0;t<3;t++){
        int mt = 3*hw + t;
        if (mt < 5){
          bf16x8 a = *reinterpret_cast<const bf16x8*>(&X[16*mt + l15][k0 + quad*8]);
          acc[t][0] = __builtin_amdgcn_mfma_f32_16x16x32_bf16(a, bz, acc[t][0], 0,0,0);
          acc[t][1] = __builtin_amdgcn_mfma_f32_16x16x32_bf16(a, br, acc[t][1], 0,0,0);
          acc[t][2] = __builtin_amdgcn_mfma_f32_16x16x32_bf16(a, bc, acc[t][2], 0,0,0);
        }
      }
    }
    for (int k8=4;k8<8;k8++){          // h half: K rows 128..256, cand gate -> acc[.][3]
      int k0 = k8*32;
      int koff = k0 + quad*8;
      bf16x8 bz = *reinterpret_cast<const bf16x8*>(&Wt[(ncol      )*256 + koff]);
      bf16x8 br = *reinterpret_cast<const bf16x8*>(&Wt[(ncol + 128)*256 + koff]);
      bf16x8 bc = *reinterpret_cast<const bf16x8*>(&Wt[(ncol + 384)*256 + koff]);
      #pragma unroll
      for (int t=0;t<3;t++){
        int mt = 3*hw + t;
        if (mt < 5){
          bf16x8 a = *reinterpret_cast<const bf16x8*>(&NE[16*mt + l15 + 8][k0 - 128 + quad*8]);
          acc[t][0] = __builtin_amdgcn_mfma_f32_16x16x32_bf16(a, bz, acc[t][0], 0,0,0);
          acc[t][1] = __builtin_amdgcn_mfma_f32_16x16x32_bf16(a, br, acc[t][1], 0,0,0);
          acc[t][3] = __builtin_amdgcn_mfma_f32_16x16x32_bf16(a, bc, acc[t][3], 0,0,0);
        }
      }
    }
    int j = ncol;
    float bjz = bgru[j], bjr = bgru[128 + j], bjc = bgru[256 + j];
    #pragma unroll
    for (int t=0;t<3;t++){
      int mt = 3*hw + t;
      if (mt < 5){
        #pragma unroll
        for (int reg=0;reg<4;reg++){
          int rl = 16*mt + quad*4 + reg;
          float z = fsig(acc[t][0][reg] + bjz);
          float r = fsig(acc[t][1][reg] + bjr);
          float cand = ftanh(acc[t][2][reg] + bjc + r*acc[t][3][reg]);
          float ho = bf2f(NE[rl + 8][j]);
          H1[rl][j] = f2bf(z*ho + (1.f - z)*cand);
        }
      }
    }
  }
  __syncthreads();
  // ---- P4: GAT-2 t + logits for 80 rows; hw0 {0,1,2}, hw1 {3,4}; Tt transposed ----
  {
    f32x4 acc[3];
    #pragma unroll
    for (int t=0;t<3;t++) acc[t] = (f32x4){0.f,0.f,0.f,0.f};
    #pragma unroll
    for (int kc=0;kc<4;kc++){
      int k0 = kc*32;
      bf16x8 bfr = *reinterpret_cast<const bf16x8*>(&Wgt[(16*cw + l15)*128 + k0 + quad*8]);
      #pragma unroll
      for (int t=0;t<3;t++){
        int mt = 3*hw + t;
        if (mt < 5){
          bf16x8 a = *reinterpret_cast<const bf16x8*>(&H1[16*mt + l15][k0 + quad*8]);
          acc[t] = __builtin_amdgcn_mfma_f32_16x16x32_bf16(a, bfr, acc[t], 0,0,0);
        }
      }
    }
    int c = 16*cw + l15;
    float bgc = bg[c], agc = ag[c];
    float lp[3][4];
    #pragma unroll
    for (int t=0;t<3;t++){
      int mt = 3*hw + t;
      if (mt < 5){
        short4 tv;
        #pragma unroll
        for (int reg=0;reg<4;reg++){
          float tt = ftanh(acc[t][reg] + bgc);
          reinterpret_cast<short*>(&tv)[reg] = f2bf(tt);
          lp[t][reg] = tt * agc;
        }
        *reinterpret_cast<short4*>(&Tt[c][16*mt + quad*4]) = tv;
      } else {
        #pragma unroll
        for (int reg=0;reg<4;reg++) lp[t][reg] = 0.f;
      }
    }
    #pragma unroll
    for (int t=0;t<3;t++)
      #pragma unroll
      for (int reg=0;reg<4;reg++){
        lp[t][reg] += __shfl_xor(lp[t][reg], 1);
        lp[t][reg] += __shfl_xor(lp[t][reg], 2);
        lp[t][reg] += __shfl_xor(lp[t][reg], 4);
        lp[t][reg] += __shfl_xor(lp[t][reg], 8);
      }
    if (l15 == 0){
      #pragma unroll
      for (int t=0;t<3;t++){
        int mt = 3*hw + t;
        if (mt < 5){
          #pragma unroll
          for (int reg=0;reg<4;reg++)
            Lp[cw][16*mt + quad*4 + reg] = lp[t][reg];
        }
      }
    }
  }
  __syncthreads();
  // ---- Ls (80 rows) + zero A2[64][0..96) ----
  if (tid < 80){
    float s = 0.f;
    #pragma unroll
    for (int i=0;i<8;i++) s += Lp[i][tid];
    Ls[tid] = s;
  }
  if (tid < 768){
    bf16x8 z8;
    #pragma unroll
    for (int q=0;q<8;q++) z8[q] = 0;
    int r = tid/12, c8 = tid%12;
    *reinterpret_cast<bf16x8*>(&A2[r][c8*8]) = z8;
  }
  __syncthreads();
  // ---- P5a: softmax + scatter into A2 (64 owned; thread tid owns row tid-8) ----
  if (tid >= 8 && tid < 72){
    int r5 = tid - 8;
    float at[16];
    float m = -1e30f;
    #pragma unroll
    for (int d=0; d<16; d++) m = fmaxf(m, Ls[li96[d] - 8]);
    float s = 0.f;
    #pragma unroll
    for (int d=0; d<16; d++){ at[d] = __expf(Ls[li96[d] - 8] - m); s += at[d]; }
    float inv = frcp(s);
    #pragma unroll
    for (int d=0; d<16; d++) A2[r5][li96[d] - 8] = f2bf(at[d]*inv);
  }
  __syncthreads();
  // ---- P5b: msg2 = A2[64][80] x T[80][128] via MFMA; 4 tiles = 2 per half ----
  {
    f32x4 acc[2];
    #pragma unroll
    for (int t=0;t<2;t++) acc[t] = (f32x4){0.f,0.f,0.f,0.f};
    #pragma unroll
    for (int kc=0;kc<3;kc++){      // K padded to 96: A2 cols [80,96) are zero
      int k0 = kc*32;
      bf16x8 bfr = *reinterpret_cast<const bf16x8*>(&Tt[16*cw + l15][k0 + quad*8]);
      #pragma unroll
      for (int t=0;t<2;t++){
        bf16x8 a = *reinterpret_cast<const bf16x8*>(&A2[16*(2*hw+t) + l15][k0 + quad*8]);
        acc[t] = __builtin_amdgcn_mfma_f32_16x16x32_bf16(a, bfr, acc[t], 0,0,0);
      }
    }
    int c = 16*cw + l15;
    #pragma unroll
    for (int t=0;t<2;t++)
      #pragma unroll
      for (int reg=0;reg<4;reg++){
        int rl = 16*(2*hw+t) + quad*4 + reg;
        X[rl][c] = f2bf(ftanh(acc[t][reg] + bf2f(NE[rl + 16][c])));
      }
  }
  __syncthreads();
  // ---- P6: GRU-2 for 64 owned; hw0 tiles {0,1}, hw1 {2,3} ----
  {
    f32x4 acc[2][4];
    #pragma unroll
    for (int t=0;t<2;t++)
      #pragma unroll
      for (int g=0;g<4;g++) acc[t][g] = (f32x4){0.f,0.f,0.f,0.f};
    int ncol = 16*cw + l15;
    for (int k8=0;k8<4;k8++){
      int k0 = k8*32;
      int koff = k0 + quad*8;
      bf16x8 bz = *reinterpret_cast<const bf16x8*>(&Wt[(ncol      )*256 + koff]);
      bf16x8 br = *reinterpret_cast<const bf16x8*>(&Wt[(ncol + 128)*256 + koff]);
      bf16x8 bc = *reinterpret_cast<const bf16x8*>(&Wt[(ncol + 256)*256 + koff]);
      #pragma unroll
      for (int t=0;t<2;t++){
        int mt = 2*hw + t;
        bf16x8 a = *reinterpret_cast<const bf16x8*>(&X[16*mt + l15][k0 + quad*8]);
        acc[t][0] = __builtin_amdgcn_mfma_f32_16x16x32_bf16(a, bz, acc[t][0], 0,0,0);
        acc[t][1] = __builtin_amdgcn_mfma_f32_16x16x32_bf16(a, br, acc[t][1], 0,0,0);
        acc[t][2] = __builtin_amdgcn_mfma_f32_16x16x32_bf16(a, bc, acc[t][2], 0,0,0);
      }
    }
    for (int k8=4;k8<8;k8++){
      int k0 = k8*32;
      int koff = k0 + quad*8;
      bf16x8 bz = *reinterpret_cast<const bf16x8*>(&Wt[(ncol      )*256 + koff]);
      bf16x8 br = *reinterpret_cast<const bf16x8*>(&Wt[(ncol + 128)*256 + koff]);
      bf16x8 bc = *reinterpret_cast<const bf16x8*>(&Wt[(ncol + 384)*256 + koff]);
      #pragma unroll
      for (int t=0;t<2;t++){
        int mt = 2*hw + t;
        bf16x8 a = *reinterpret_cast<const bf16x8*>(&H1[16*mt + l15 + 8][k0 - 128 + quad*8]);
        acc[t][0] = __builtin_amdgcn_mfma_f32_16x16x32_bf16(a, bz, acc[t][0], 0,0,0);
        acc[t][1] = __builtin_amdgcn_mfma_f32_16x16x32_bf16(a, br, acc[t][1], 0,0,0);
        acc[t][3] = __builtin_amdgcn_mfma_f32_16x16x32_bf16(a, bc, acc[t][3], 0,0,0);
      }
    }
    __syncthreads();   // X is MFMA input above, epilogue output below
    int j = ncol;
    float bjz = bgru[j], bjr = bgru[128 + j], bjc = bgru[256 + j];
    #pragma unroll
    for (int t=0;t<2;t++){
      int mt = 2*hw + t;
      #pragma unroll
      for (int reg=0;reg<4;reg++){
        int rl = 16*mt + quad*4 + reg;
        float z = fsig(acc[t][0][reg] + bjz);
        float r = fsig(acc[t][1][reg] + bjr);
        float cand = ftanh(acc[t][2][reg] + bjc + r*acc[t][3][reg]);
        float ho = bf2f(H1[rl + 8][j]);
        X[rl][j] = f2bf(z*ho + (1.f - z)*cand);
      }
    }
  }
  __syncthreads();
  if (tid < 64*16){
    int r = tid >> 4, c8 = tid & 15;
    *reinterpret_cast<bf16x8*>(&hout[(long)((b<<10) + n0 + r)*128 + c8*8]) =
        *reinterpret_cast<const bf16x8*>(&X[r][c8*8]);
  }
}

// Fused decoder + dest-attn + sparsemax + dual-vars, 1024 threads (r3 verbatim).
__global__ __launch_bounds__(1024,4) void k_decdas(const short* __restrict__ hn, const int* __restrict__ adj,
    const int* __restrict__ invadj, const short* __restrict__ Wpq, const float* __restrict__ b1,
    const float* __restrict__ W2, const float* __restrict__ b2_,
    const short* __restrict__ Wu1t, const float* __restrict__ bu1, const float* __restrict__ Wu2,
    const float* __restrict__ bu2_, float* __restrict__ norm_, float* __restrict__ dv){
  __shared__ short Hs[112][136];
  __shared__ short PQb[112][132];
  __shared__ short NSs[64][136];
  __shared__ int adjL[64][16];
  __shared__ float dvp[64][4];
  __shared__ float b1s[64], w2s[64], bu1s[64], wu2s[64];
  int tid = threadIdx.x;
  int blk = blockIdx.x;
  int b = blk >> 4;
  int n0 = (blk & 15) << 6;
  if (tid < 64){ b1s[tid] = b1[tid]; w2s[tid] = W2[tid]; bu1s[tid] = bu1[tid]; wu2s[tid] = Wu2[tid]; }
  for (int idx=tid; idx<112*16; idx+=1024){
    int r = idx >> 4, c8 = idx & 15;
    int g = (b << 10) + ((n0 - 24 + r) & 1023);
    *reinterpret_cast<bf16x8*>(&Hs[r][c8*8]) =
        *reinterpret_cast<const bf16x8*>(&hn[(long)g*128 + c8*8]);
  }
  {
    int r = tid >> 4, d = tid & 15;
    int a = adj[((b<<10) + n0 + r)*16 + d];
    adjL[r][d] = (a - n0 + 24) & 1023;
  }
  __syncthreads();
  int w = tid >> 6, lane = tid & 63;
  int l15 = lane & 15, quad = lane >> 4;
  int cw = w & 7, hw = w >> 3;
  // ---- PQ GEMM: 7 tiles; hw0 {0..3}, hw1 {4..6} ----
  {
    f32x4 acc[4];
    #pragma unroll
    for (int t=0;t<4;t++) acc[t] = (f32x4){0.f,0.f,0.f,0.f};
    #pragma unroll
    for (int kc=0;kc<4;kc++){
      int k0 = kc*32;
      bf16x8 bfr = *reinterpret_cast<const bf16x8*>(&Wpq[(16*cw + l15)*128 + k0 + quad*8]);
      #pragma unroll
      for (int t=0;t<4;t++){
        int mt = 4*hw + t;
        if (mt < 7){
          bf16x8 a = *reinterpret_cast<const bf16x8*>(&Hs[16*mt + l15][k0 + quad*8]);
          acc[t] = __builtin_amdgcn_mfma_f32_16x16x32_bf16(a, bfr, acc[t], 0,0,0);
        }
      }
    }
    int c = 16*cw + l15;
    #pragma unroll
    for (int t=0;t<4;t++){
      int mt = 4*hw + t;
      if (mt < 7){
        #pragma unroll
        for (int reg=0;reg<4;reg++)
          PQb[16*mt + quad*4 + reg][c] = f2bf(acc[t][reg]);
      }
    }
  }
  // ---- node_states gather: 1024 items, one per thread ----
  {
    int r = tid >> 4, c8 = tid & 15;
    float acc8[8] = {0,0,0,0,0,0,0,0};
    #pragma unroll 4
    for (int d=0; d<16; d++){
      bf16x8 hv = *reinterpret_cast<const bf16x8*>(&Hs[adjL[r][d]][c8*8]);
      #pragma unroll
      for (int q=0;q<8;q++) acc8[q] += bf2f(hv[q]);
    }
    bf16x8 sv;
    #pragma unroll
    for (int q=0;q<8;q++) sv[q] = f2bf(acc8[q]);
    *reinterpret_cast<bf16x8*>(&NSs[r][c8*8]) = sv;
  }
  __syncthreads();
  // ---- dual MLP MFMA on waves 0-7: col group c4 = w&3, row half h2 = w>>2 ----
  if (w < 8){
    int c4 = w & 3, h2 = w >> 2;
    f32x4 acc[2];
    #pragma unroll
    for (int t=0;t<2;t++) acc[t] = (f32x4){0.f,0.f,0.f,0.f};
    #pragma unroll
    for (int kc=0;kc<4;kc++){
      int k0 = kc*32;
      bf16x8 bfr = *reinterpret_cast<const bf16x8*>(&Wu1t[(16*c4 + l15)*128 + k0 + quad*8]);
      #pragma unroll
      for (int t=0;t<2;t++){
        bf16x8 a = *reinterpret_cast<const bf16x8*>(&NSs[16*(2*h2+t) + l15][k0 + quad*8]);
        acc[t] = __builtin_amdgcn_mfma_f32_16x16x32_bf16(a, bfr, acc[t], 0,0,0);
      }
    }
    int n = 16*c4 + l15;
    float bn = bu1s[n], wn = wu2s[n];
    #pragma unroll
    for (int t=0;t<2;t++){
      #pragma unroll
      for (int reg=0;reg<4;reg++){
        float p = ftanh(acc[t][reg] + bn) * wn;
        p += __shfl_xor(p, 1);
        p += __shfl_xor(p, 2);
        p += __shfl_xor(p, 4);
        p += __shfl_xor(p, 8);
        if (l15 == 0) dvp[16*(2*h2+t) + quad*4 + reg][c4] = p;
      }
    }
  }
  __syncthreads();
  float* nws = reinterpret_cast<float*>(&Hs[0][0]);   // [96][17]
  float b2v = b2_[0];
  for (int e = tid; e < 96*16; e += 1024){
    int rr = e >> 4, d = e & 15;
    int wnode = (n0 + rr - 16) & 1023;
    int wg = (b<<10) + wnode;
    int a = adj[wg*16 + d];
    int al = (a - n0 + 24) & 1023;
    int wl = rr + 8;
    float p = 0.f;
    #pragma unroll 8
    for (int c=0;c<64;c++)
      p += ftanh(bf2f(PQb[al][c]) + bf2f(PQb[wl][64 + c]) + b1s[c]) * w2s[c];
    nws[rr*17 + d] = p + b2v;
  }
  __syncthreads();
  if (tid < 64){
    float val = dvp[tid][0]+dvp[tid][1]+dvp[tid][2]+dvp[tid][3];
    dv[(b<<10) + n0 + tid] = fmaxf(val + bu2_[0], 0.f);
  }
  float* datt = reinterpret_cast<float*>(&PQb[0][0]); // [80][17]
  if (tid < 80){
    int wnode = (n0 + tid - 8) & 1023;
    int wg = (b<<10) + wnode;
    float vals[16];
    float m = -1e30f;
    #pragma unroll
    for (int d=0; d<16; d++){
      int iv = invadj[wg*16 + d];
      int il = (iv - n0 + 16) & 1023;
      vals[d] = nws[il*17 + d];
      m = fmaxf(m, vals[d]);
    }
    float s = 0.f;
    #pragma unroll
    for (int d=0; d<16; d++){ vals[d] = __expf(vals[d]-m); s += vals[d]; }
    float inv = frcp(s);
    #pragma unroll
    for (int d=0; d<16; d++) datt[tid*17 + d] = vals[d]*inv;
  }
  __syncthreads();
  if (tid < 64){
    int vg = (b<<10) + n0 + tid;
    float z[16], s[16];
    #pragma unroll
    for (int d=0; d<16; d++){
      int al = adjL[tid][d] - 16;
      z[d] = datt[al*17 + d];
      s[d] = z[d];
    }
    #pragma unroll
    for (int k2 = 2; k2 <= 16; k2 <<= 1){
      #pragma unroll
      for (int jj = k2 >> 1; jj > 0; jj >>= 1){
        #pragma unroll
        for (int i = 0; i < 16; i++){
          int l = i ^ jj;
          if (l > i){
            bool up = ((i & k2) == 0);
            float a = s[i], bb = s[l];
            bool sw = up ? (a > bb) : (a < bb);
            if (sw){ s[i]=bb; s[l]=a; }
          }
        }
      }
    }
    float cs = 0.f, zcs = 0.f; int kz = 1;
    #pragma unroll
    for (int j=0;j<16;j++){
      float zj = s[15-j];
      cs += zj;
      if (1.f + (float)(j+1)*zj > cs){ kz = j+1; zcs = cs; }
    }
    float tau = (zcs - 1.f)/(float)kz;
    #pragma unroll
    for (int d=0; d<16; d++) norm_[(long)vg*16 + d] = fmaxf(z[d]-tau, 0.f);
  }
}

// Flow solver, halo-redundant stencil form (r1 verbatim).
__global__ __launch_bounds__(256) void k_flowfin(const float* __restrict__ norm_,
    const float* __restrict__ dem, const int* __restrict__ invadj, const float* __restrict__ dv,
    float* __restrict__ out){
  __shared__ float nrmS[224*17];
  __shared__ float sbuf[2][224];
  __shared__ float red[4];
  int tid = threadIdx.x;
  int blk = blockIdx.x;
  int b = blk >> 4;
  int t0 = (blk & 15) << 6;
  for (int e=tid; e<224*4; e+=256){
    int r = e >> 2, q4 = e & 3;
    int v = (t0 - 80 + r) & 1023;
    float4 x = reinterpret_cast<const float4*>(&norm_[(long)((b<<10) + v)*16])[q4];
    nrmS[r*17 + q4*4+0] = x.x; nrmS[r*17 + q4*4+1] = x.y;
    nrmS[r*17 + q4*4+2] = x.z; nrmS[r*17 + q4*4+3] = x.w;
  }
  bool act = tid < 224;
  int r = tid;
  float dm = 0.f; int gv = 0;
  int ivl[16];
  if (act){
    int v = (t0 - 80 + r) & 1023;
    gv = (b<<10) + v;
    dm = dem[gv];
    #pragma unroll
    for (int d4=0; d4<4; d4++){
      int4 i4 = reinterpret_cast<const int4*>(&invadj[(long)gv*16])[d4];
      int t;
      t = (i4.x - t0 + 80) & 1023; ivl[d4*4+0] = t < 224 ? t : 223;
      t = (i4.y - t0 + 80) & 1023; ivl[d4*4+1] = t < 224 ? t : 223;
      t = (i4.z - t0 + 80) & 1023; ivl[d4*4+2] = t < 224 ? t : 223;
      t = (i4.w - t0 + 80) & 1023; ivl[d4*4+3] = t < 224 ? t : 223;
    }
    sbuf[0][r] = 0.f;
  }
  __syncthreads();
  float nrg[16];
  if (act){
    #pragma unroll
    for (int d=0; d<16; d++) nrg[d] = nrmS[ivl[d]*17 + d];
  }
  int p = 0;
  float s = 0.f;
  for (int it=0; it<10; it++){
    if (act){
      float inflow = 0.f;
      #pragma unroll
      for (int d=0; d<16; d++) inflow += nrg[d]*sbuf[p][ivl[d]];
      s = fmaxf(inflow - dm, 0.f);
      sbuf[1-p][r] = s;
    }
    p ^= 1;
    __syncthreads();
  }
  float partF = 0.f, partD = 0.f, partDD = 0.f;
  if (act && r >= 80 && r < 144){
    float nr2 = 0.f;
    #pragma unroll
    for (int d=0; d<16; d++){ float nv = nrmS[r*17 + d]; nr2 += nv*nv; }
    partF = nr2 * s * s;
    float dvv = dv[gv];
    float f = 0.f, vel = 0.f;
    #pragma unroll
    for (int it=0; it<10; it++){
      float g = 2.f*f + dvv;
      vel = 0.9f*vel - 0.01f*g;
      f = fmaxf(f + vel, 0.f);
    }
    partD = f*f + dvv*f;
    partDD = dvv * dm;
  }
  float val = partF - 16.f*partD + partDD;   // out[b] = sum F - (16*sum D - sum DD)
  #pragma unroll
  for (int off=32; off>0; off>>=1) val += __shfl_down(val, off);
  if ((tid & 63) == 0) red[tid>>6] = val;
  __syncthreads();
  if (tid == 0) atomicAdd(&out[b], red[0]+red[1]+red[2]+red[3]);
}

extern "C" void kernel_launch(void* const* d_in, const int* in_sizes, int n_in,
                              void* d_out, int out_size, void* d_ws, size_t ws_size,
                              hipStream_t stream){
  (void)in_sizes; (void)n_in; (void)out_size; (void)ws_size;
  const float* demands = (const float*)d_in[0];
  const float* nf      = (const float*)d_in[1];
  const float* emb     = (const float*)d_in[4];
  const float* Wenc    = (const float*)d_in[5];
  const float* benc    = (const float*)d_in[6];
  const float* Wgat    = (const float*)d_in[7];
  const float* bgat    = (const float*)d_in[8];
  const float* agat    = (const float*)d_in[9];
  const float* Wgx     = (const float*)d_in[10];
  const float* Wgh     = (const float*)d_in[11];
  const float* bgru    = (const float*)d_in[12];
  const float* Wd1     = (const float*)d_in[13];
  const float* bd1     = (const float*)d_in[14];
  const float* Wd2     = (const float*)d_in[15];
  const float* bd2     = (const float*)d_in[16];
  const float* Wu1     = (const float*)d_in[17];
  const float* bu1     = (const float*)d_in[18];
  const float* Wu2     = (const float*)d_in[19];
  const float* bu2     = (const float*)d_in[20];
  const int* adj       = (const int*)d_in[21];
  const int* invadj    = (const int*)d_in[22];

  float* ws    = (float*)d_ws;
  short* hnB   = (short*)(ws + OFF_HNB);
  float* nrm   = ws + OFF_NORM;
  float* dv    = ws + OFF_DV;
  short* wt    = (short*)(ws + OFF_WT);
  short* wtg   = (short*)(ws + OFF_WTG);
  short* wpq   = (short*)(ws + OFF_WPQ);
  short* wu1t  = (short*)(ws + OFF_WU1T);
  short* wenct = (short*)(ws + OFF_WENCT);

  k_pre<<<704, 256, 0, stream>>>(Wgx, Wgh, Wgat, Wd1, Wu1, Wenc, wt, wtg, wpq, wu1t, wenct,
                                 (float*)d_out);
  k_mega<<<BV/64, 1024, 0, stream>>>(emb, nf, wenct, benc, adj, wtg, bgat, agat, wt, bgru, hnB);
  k_decdas<<<BV/64, 1024, 0, stream>>>(hnB, adj, invadj, wpq, bd1, Wd2, bd2,
                                       wu1t, bu1, Wu2, bu2, nrm, dv);
  k_flowfin<<<B*16, 256, 0, stream>>>(nrm, demands, invadj, dv, (float*)d_out);
}

// Round 6
// 174.297 us; speedup vs baseline: 2.0258x; 1.0690x over previous
//
#include <hip/hip_runtime.h>
#include <hip/hip_bf16.h>

#define B 16
#define V 1024
#define D 16
#define E 64
#define F 16
#define H 128
#define HD 64
#define BV (B*V)      // 16384
#define BVD (B*V*D)   // 262144

// ---- workspace layout (float offsets) ----
#define OFF_HNB      0                         // hnode layer2 bf16 (BV*H shorts)
#define OFF_NORM     (OFF_HNB + BV*H/2)        // sparsemax output fp32 (BVD)
#define OFF_DV       (OFF_NORM + BVD)          // dual vars (BV)
#define OFF_WT       (OFF_DV + BV)             // 512x256 bf16 GRU weights
#define OFF_WTG      (OFF_WT + 65536)          // 128x128 bf16 GAT weights
#define OFF_WPQ      (OFF_WTG + 8192)          // 128x128 bf16 dec [P|Q] weights
#define OFF_WU1T     (OFF_WPQ + 8192)          // 64x128 bf16 dual W1^T
#define OFF_WENCT    (OFF_WU1T + 4096)         // 128x96 bf16 enc W^T (K padded 80->96)

typedef __attribute__((ext_vector_type(8))) short bf16x8;
typedef __attribute__((ext_vector_type(4))) float f32x4;

__device__ __forceinline__ short f2bf(float f){
  __hip_bfloat16 b = __float2bfloat16(f);
  return *reinterpret_cast<short*>(&b);
}
__device__ __forceinline__ float bf2f(short s){
  __hip_bfloat16 b; *reinterpret_cast<short*>(&b) = s;
  return __bfloat162float(b);
}
__device__ __forceinline__ float frcp(float x){ return __builtin_amdgcn_rcpf(x); }
__device__ __forceinline__ float fsig(float x){ return frcp(1.f + __expf(-x)); }
__device__ __forceinline__ float ftanh(float x){
  float e = __expf(-2.f*fabsf(x));
  float r = (1.f - e)*frcp(1.f + e);
  return copysignf(r, x);
}

// ---- weight packs + output zeroing (runs first in stream) ----
__global__ __launch_bounds__(256) void k_pre(const float* __restrict__ Wx, const float* __restrict__ Wh,
    const float* __restrict__ Wg, const float* __restrict__ W1, const float* __restrict__ Wu1,
    const float* __restrict__ Wenc,
    short* __restrict__ Wt, short* __restrict__ Wgt, short* __restrict__ Wpq,
    short* __restrict__ Wu1t, short* __restrict__ Wenct, float* __restrict__ outz){
  int bid = blockIdx.x, tid = threadIdx.x;
  if (bid == 0 && tid < 16) outz[tid] = 0.f;   // k_flowfin atomicAdds into this
  if (bid < 512){
    int n = bid, k = tid;
    int g = n >> 7, j = n & 127;
    float v;
    if (g == 0)      v = (k < 128) ? Wx[k*384 + j]       : Wh[(k-128)*384 + j];
    else if (g == 1) v = (k < 128) ? Wx[k*384 + 128 + j] : Wh[(k-128)*384 + 128 + j];
    else if (g == 2) v = (k < 128) ? Wx[k*384 + 256 + j] : 0.f;
    else             v = (k < 128) ? 0.f                 : Wh[(k-128)*384 + 256 + j];
    Wt[n*256 + k] = f2bf(v);
    return;
  }
  if (bid < 576){
    int idx = (bid-512)*256 + tid;
    int n = idx >> 7, k = idx & 127;
    Wgt[n*128 + k] = f2bf(Wg[k*128 + n]);
    return;
  }
  if (bid < 608){
    int idx = (bid-576)*256 + tid;
    int n = idx >> 7, k = idx & 127;
    float wb = W1[(k+128)*HD + n];
    float wa = W1[k*HD + n];
    Wpq[n*128 + k]      = f2bf(wa + wb);
    Wpq[(64+n)*128 + k] = f2bf(wb);
    return;
  }
  if (bid < 640){
    int idx = (bid-608)*256 + tid;
    int n = idx >> 7, k = idx & 127;
    Wu1t[n*128 + k] = f2bf(Wu1[k*HD + n]);
    return;
  }
  {
    int nn = (bid-640)*2 + (tid >> 7);
    int kk = tid & 127;
    if (kk < 96) Wenct[nn*96 + kk] = f2bf(kk < 80 ? Wenc[kk*128 + nn] : 0.f);
  }
}

// MEGA: r3 structure (96-frame / 64-owned, 512 threads, 1 block/CU; MFMA-ized
// msg phases, Tt transposed, adj prefetch). r5 change: E1+E2 merged — 4
// threads/row hold the 16 emb floats in regs, quad shfl-reduce the norm,
// scale in-register, single global pass and one barrier fewer.
// (Measured: 2 blocks/CU, 16 waves, and grid fusion are all net-negative.)
__global__ __launch_bounds__(512,2) void k_mega(const float* __restrict__ emb, const float* __restrict__ nf,
    const short* __restrict__ Wenct, const float* __restrict__ benc, const int* __restrict__ adj,
    const short* __restrict__ Wgt, const float* __restrict__ bg, const float* __restrict__ ag,
    const short* __restrict__ Wt, const float* __restrict__ bgru, short* __restrict__ hout){
  __shared__ short NE[96][136];
  __shared__ short Tt[128][104];   // transposed GAT t: Tt[col c][frame row j]
  __shared__ short H1[80][136];
  __shared__ short X[80][136];
  __shared__ short A2[80][104];    // sparse attention matrix (bf16)
  __shared__ float Lp[8][96];
  __shared__ float Ls[96];
  short (*As)[104] = reinterpret_cast<short(*)[104]>(&H1[0][0]);  // enc staging overlay

  int tid = threadIdx.x;
  int blk = blockIdx.x;
  int b = blk >> 4;
  int n0 = (blk & 15) << 6;
  int w = tid >> 6, lane = tid & 63;
  int l15 = lane & 15, quad = lane >> 4;

  // ---- adj prefetch: thread tid<80 owns frame-80 row tid (node n0-8+tid) ----
  int li96[16];
  if (tid < 80){
    int wg = (b<<10) + ((n0 - 8 + tid) & 1023);
    const int4* a4 = reinterpret_cast<const int4*>(&adj[(long)wg*16]);
    #pragma unroll
    for (int d4=0; d4<4; d4++){
      int4 i4 = a4[d4];
      li96[d4*4+0] = (i4.x - n0 + 16) & 1023;
      li96[d4*4+1] = (i4.y - n0 + 16) & 1023;
      li96[d4*4+2] = (i4.z - n0 + 16) & 1023;
      li96[d4*4+3] = (i4.w - n0 + 16) & 1023;
    }
  }

  // ---- E12: fused emb norm + scale + stage As[96][0..64); 4 threads/row ----
  if (tid < 384){
    int r = tid >> 2, q = tid & 3;
    int v = (n0 - 16 + r) & 1023;
    const float4* e4 = reinterpret_cast<const float4*>(&emb[v*E]);
    float4 x0 = e4[q*4+0], x1 = e4[q*4+1], x2 = e4[q*4+2], x3 = e4[q*4+3];
    float ss = x0.x*x0.x + x0.y*x0.y + x0.z*x0.z + x0.w*x0.w
             + x1.x*x1.x + x1.y*x1.y + x1.z*x1.z + x1.w*x1.w
             + x2.x*x2.x + x2.y*x2.y + x2.z*x2.z + x2.w*x2.w
             + x3.x*x3.x + x3.y*x3.y + x3.z*x3.z + x3.w*x3.w;
    ss += __shfl_xor(ss, 1);
    ss += __shfl_xor(ss, 2);
    float iv = frcp(fmaxf(sqrtf(ss), 1.f));
    short4 s;
    s.x=f2bf(x0.x*iv); s.y=f2bf(x0.y*iv); s.z=f2bf(x0.z*iv); s.w=f2bf(x0.w*iv);
    *reinterpret_cast<short4*>(&As[r][q*16 + 0]) = s;
    s.x=f2bf(x1.x*iv); s.y=f2bf(x1.y*iv); s.z=f2bf(x1.z*iv); s.w=f2bf(x1.w*iv);
    *reinterpret_cast<short4*>(&As[r][q*16 + 4]) = s;
    s.x=f2bf(x2.x*iv); s.y=f2bf(x2.y*iv); s.z=f2bf(x2.z*iv); s.w=f2bf(x2.w*iv);
    *reinterpret_cast<short4*>(&As[r][q*16 + 8]) = s;
    s.x=f2bf(x3.x*iv); s.y=f2bf(x3.y*iv); s.z=f2bf(x3.z*iv); s.w=f2bf(x3.w*iv);
    *reinterpret_cast<short4*>(&As[r][q*16 + 12]) = s;
  }
  for (int e=tid; e<96*4; e+=512){
    int r = e >> 2, q = e & 3;
    int m = (b<<10) + ((n0 - 16 + r) & 1023);
    float4 x = reinterpret_cast<const float4*>(&nf[(long)m*F])[q];
    short4 s; s.x=f2bf(x.x); s.y=f2bf(x.y); s.z=f2bf(x.z); s.w=f2bf(x.w);
    *reinterpret_cast<short4*>(&As[r][64 + q*4]) = s;
    short4 z; z.x=0; z.y=0; z.z=0; z.w=0;
    *reinterpret_cast<short4*>(&As[r][80 + q*4]) = z;
  }
  __syncthreads();
  // ---- E3: encoder MFMA (96 rows x 128 cols, K=96); wave w owns cols 16w..16w+16 ----
  {
    f32x4 acc[6];
    #pragma unroll
    for (int mt=0;mt<6;mt++) acc[mt] = (f32x4){0.f,0.f,0.f,0.f};
    #pragma unroll
    for (int kc=0;kc<3;kc++){
      int k0 = kc*32;
      bf16x8 bfr = *reinterpret_cast<const bf16x8*>(&Wenct[(16*w + l15)*96 + k0 + quad*8]);
      #pragma unroll
      for (int mt=0;mt<6;mt++){
        bf16x8 a = *reinterpret_cast<const bf16x8*>(&As[16*mt + l15][k0 + quad*8]);
        acc[mt] = __builtin_amdgcn_mfma_f32_16x16x32_bf16(a, bfr, acc[mt], 0,0,0);
      }
    }
    int c = 16*w + l15;
    float bb = benc[c];
    #pragma unroll
    for (int mt=0;mt<6;mt++)
      #pragma unroll
      for (int reg=0;reg<4;reg++)
        NE[16*mt + quad*4 + reg][c] = f2bf(acc[mt][reg] + bb);
  }
  __syncthreads();
  // ---- P1: GAT-1 t + logits for 96 rows; writes Tt transposed ----
  {
    f32x4 acc[6];
    #pragma unroll
    for (int mt=0;mt<6;mt++) acc[mt] = (f32x4){0.f,0.f,0.f,0.f};
    #pragma unroll
    for (int kc=0;kc<4;kc++){
      int k0 = kc*32;
      bf16x8 bfr = *reinterpret_cast<const bf16x8*>(&Wgt[(16*w + l15)*128 + k0 + quad*8]);
      #pragma unroll
      for (int mt=0;mt<6;mt++){
        bf16x8 a = *reinterpret_cast<const bf16x8*>(&NE[16*mt + l15][k0 + quad*8]);
        acc[mt] = __builtin_amdgcn_mfma_f32_16x16x32_bf16(a, bfr, acc[mt], 0,0,0);
      }
    }
    int c = 16*w + l15;
    float bgc = bg[c], agc = ag[c];
    float lp[6][4];
    #pragma unroll
    for (int mt=0;mt<6;mt++){
      short4 tv;
      #pragma unroll
      for (int reg=0;reg<4;reg++){
        float t = ftanh(acc[mt][reg] + bgc);
        reinterpret_cast<short*>(&tv)[reg] = f2bf(t);
        lp[mt][reg] = t * agc;
      }
      *reinterpret_cast<short4*>(&Tt[c][16*mt + quad*4]) = tv;
    }
    #pragma unroll
    for (int mt=0;mt<6;mt++)
      #pragma unroll
      for (int reg=0;reg<4;reg++){
        lp[mt][reg] += __shfl_xor(lp[mt][reg], 1);
        lp[mt][reg] += __shfl_xor(lp[mt][reg], 2);
        lp[mt][reg] += __shfl_xor(lp[mt][reg], 4);
        lp[mt][reg] += __shfl_xor(lp[mt][reg], 8);
      }
    if (l15 == 0){
      #pragma unroll
      for (int mt=0;mt<6;mt++)
        #pragma unroll
        for (int reg=0;reg<4;reg++)
          Lp[w][16*mt + quad*4 + reg] = lp[mt][reg];
    }
  }
  __syncthreads();
  // ---- Ls (96 rows) + zero A2[80][0..96) ----
  if (tid < 96){
    float s = 0.f;
    #pragma unroll
    for (int i=0;i<8;i++) s += Lp[i][tid];
    Ls[tid] = s;
  }
  {
    bf16x8 z8;
    #pragma unroll
    for (int q=0;q<8;q++) z8[q] = 0;
    for (int idx=tid; idx<960; idx+=512){
      int r = idx/12, c8 = idx%12;
      *reinterpret_cast<bf16x8*>(&A2[r][c8*8]) = z8;
    }
  }
  __syncthreads();
  // ---- P2a: softmax + scatter into A2 (80 nodes) ----
  if (tid < 80){
    float at[16];
    float m = -1e30f;
    #pragma unroll
    for (int d=0; d<16; d++) m = fmaxf(m, Ls[li96[d]]);
    float s = 0.f;
    #pragma unroll
    for (int d=0; d<16; d++){ at[d] = __expf(Ls[li96[d]] - m); s += at[d]; }
    float inv = frcp(s);
    #pragma unroll
    for (int d=0; d<16; d++) A2[tid][li96[d]] = f2bf(at[d]*inv);
  }
  __syncthreads();
  // ---- P2b: msg1 = A2[80][96] x T[96][128] via MFMA; x1 -> X[0..80) ----
  {
    f32x4 acc[5];
    #pragma unroll
    for (int mt=0;mt<5;mt++) acc[mt] = (f32x4){0.f,0.f,0.f,0.f};
    #pragma unroll
    for (int kc=0;kc<3;kc++){
      int k0 = kc*32;
      bf16x8 bfr = *reinterpret_cast<const bf16x8*>(&Tt[16*w + l15][k0 + quad*8]);
      #pragma unroll
      for (int mt=0;mt<5;mt++){
        bf16x8 a = *reinterpret_cast<const bf16x8*>(&A2[16*mt + l15][k0 + quad*8]);
        acc[mt] = __builtin_amdgcn_mfma_f32_16x16x32_bf16(a, bfr, acc[mt], 0,0,0);
      }
    }
    int c = 16*w + l15;
    #pragma unroll
    for (int mt=0;mt<5;mt++)
      #pragma unroll
      for (int reg=0;reg<4;reg++){
        int rl = 16*mt + quad*4 + reg;
        X[rl][c] = f2bf(ftanh(acc[mt][reg] + bf2f(NE[rl + 8][c])));
      }
  }
  __syncthreads();
  // ---- P3: GRU-1 for 80 rows ----
  {
    f32x4 acc[5][4];
    #pragma unroll
    for (int mt=0;mt<5;mt++)
      #pragma unroll
      for (int g=0;g<4;g++) acc[mt][g] = (f32x4){0.f,0.f,0.f,0.f};
    for (int k8=0;k8<8;k8++){
      int k0 = k8*32;
      int gg = (k8 < 4) ? 2 : 3;
      int ncol = 16*w + l15;
      int koff = k0 + quad*8;
      bf16x8 bz = *reinterpret_cast<const bf16x8*>(&Wt[(ncol      )*256 + koff]);
      bf16x8 br = *reinterpret_cast<const bf16x8*>(&Wt[(ncol + 128)*256 + koff]);
      bf16x8 bc = *reinterpret_cast<const bf16x8*>(&Wt[(ncol + gg*128)*256 + koff]);
      #pragma unroll
      for (int mt=0;mt<5;mt++){
        bf16x8 a;
        if (k8 < 4) a = *reinterpret_cast<const bf16x8*>(&X[16*mt + l15][k0 + quad*8]);
        else        a = *reinterpret_cast<const bf16x8*>(&NE[16*mt + l15 + 8][k0 - 128 + quad*8]);
        acc[mt][0]  = __builtin_amdgcn_mfma_f32_16x16x32_bf16(a, bz, acc[mt][0], 0,0,0);
        acc[mt][1]  = __builtin_amdgcn_mfma_f32_16x16x32_bf16(a, br, acc[mt][1], 0,0,0);
        acc[mt][gg] = __builtin_amdgcn_mfma_f32_16x16x32_bf16(a, bc, acc[mt][gg], 0,0,0);
      }
    }
    int j = 16*w + l15;
    float bjz = bgru[j], bjr = bgru[128 + j], bjc = bgru[256 + j];
    #pragma unroll
    for (int mt=0;mt<5;mt++){
      #pragma unroll
      for (int reg=0;reg<4;reg++){
        int rl = 16*mt + quad*4 + reg;
        float z = fsig(acc[mt][0][reg] + bjz);
        float r = fsig(acc[mt][1][reg] + bjr);
        float cand = ftanh(acc[mt][2][reg] + bjc + r*acc[mt][3][reg]);
        float ho = bf2f(NE[rl + 8][j]);
        H1[rl][j] = f2bf(z*ho + (1.f - z)*cand);
      }
    }
  }
  __syncthreads();
  // ---- P4: GAT-2 t + logits for 80 rows; writes Tt transposed ----
  {
    f32x4 acc[5];
    #pragma unroll
    for (int mt=0;mt<5;mt++) acc[mt] = (f32x4){0.f,0.f,0.f,0.f};
    #pragma unroll
    for (int kc=0;kc<4;kc++){
      int k0 = kc*32;
      bf16x8 bfr = *reinterpret_cast<const bf16x8*>(&Wgt[(16*w + l15)*128 + k0 + quad*8]);
      #pragma unroll
      for (int mt=0;mt<5;mt++){
        bf16x8 a = *reinterpret_cast<const bf16x8*>(&H1[16*mt + l15][k0 + quad*8]);
        acc[mt] = __builtin_amdgcn_mfma_f32_16x16x32_bf16(a, bfr, acc[mt], 0,0,0);
      }
    }
    int c = 16*w + l15;
    float bgc = bg[c], agc = ag[c];
    float lp[5][4];
    #pragma unroll
    for (int mt=0;mt<5;mt++){
      short4 tv;
      #pragma unroll
      for (int reg=0;reg<4;reg++){
        float t = ftanh(acc[mt][reg] + bgc);
        reinterpret_cast<short*>(&tv)[reg] = f2bf(t);
        lp[mt][reg] = t * agc;
      }
      *reinterpret_cast<short4*>(&Tt[c][16*mt + quad*4]) = tv;
    }
    #pragma unroll
    for (int mt=0;mt<5;mt++)
      #pragma unroll
      for (int reg=0;reg<4;reg++){
        lp[mt][reg] += __shfl_xor(lp[mt][reg], 1);
        lp[mt][reg] += __shfl_xor(lp[mt][reg], 2);
        lp[mt][reg] += __shfl_xor(lp[mt][reg], 4);
        lp[mt][reg] += __shfl_xor(lp[mt][reg], 8);
      }
    if (l15 == 0){
      #pragma unroll
      for (int mt=0;mt<5;mt++)
        #pragma unroll
        for (int reg=0;reg<4;reg++)
          Lp[w][16*mt + quad*4 + reg] = lp[mt][reg];
    }
  }
  __syncthreads();
  // ---- Ls (80 rows) + zero A2[64][0..96) ----
  if (tid < 80){
    float s = 0.f;
    #pragma unroll
    for (int i=0;i<8;i++) s += Lp[i][tid];
    Ls[tid] = s;
  }
  {
    bf16x8 z8;
    #pragma unroll
    for (int q=0;q<8;q++) z8[q] = 0;
    for (int idx=tid; idx<768; idx+=512){
      int r = idx/12, c8 = idx%12;
      *reinterpret_cast<bf16x8*>(&A2[r][c8*8]) = z8;
    }
  }
  __syncthreads();
  // ---- P5a: softmax + scatter into A2 (64 owned; thread tid owns row tid-8) ----
  if (tid >= 8 && tid < 72){
    int r5 = tid - 8;
    float at[16];
    float m = -1e30f;
    #pragma unroll
    for (int d=0; d<16; d++) m = fmaxf(m, Ls[li96[d] - 8]);
    float s = 0.f;
    #pragma unroll
    for (int d=0; d<16; d++){ at[d] = __expf(Ls[li96[d] - 8] - m); s += at[d]; }
    float inv = frcp(s);
    #pragma unroll
    for (int d=0; d<16; d++) A2[r5][li96[d] - 8] = f2bf(at[d]*inv);
  }
  __syncthreads();
  // ---- P5b: msg2 = A2[64][80] x T[80][128] via MFMA; x2 -> X[0..64) ----
  {
    f32x4 acc[4];
    #pragma unroll
    for (int mt=0;mt<4;mt++) acc[mt] = (f32x4){0.f,0.f,0.f,0.f};
    #pragma unroll
    for (int kc=0;kc<3;kc++){      // K padded to 96: A2 cols [80,96) are zero
      int k0 = kc*32;
      bf16x8 bfr = *reinterpret_cast<const bf16x8*>(&Tt[16*w + l15][k0 + quad*8]);
      #pragma unroll
      for (int mt=0;mt<4;mt++){
        bf16x8 a = *reinterpret_cast<const bf16x8*>(&A2[16*mt + l15][k0 + quad*8]);
        acc[mt] = __builtin_amdgcn_mfma_f32_16x16x32_bf16(a, bfr, acc[mt], 0,0,0);
      }
    }
    int c = 16*w + l15;
    #pragma unroll
    for (int mt=0;mt<4;mt++)
      #pragma unroll
      for (int reg=0;reg<4;reg++){
        int rl = 16*mt + quad*4 + reg;
        X[rl][c] = f2bf(ftanh(acc[mt][reg] + bf2f(NE[rl + 16][c])));
      }
  }
  __syncthreads();
  // ---- P6: GRU-2 for 64 owned ----
  {
    f32x4 acc[4][4];
    #pragma unroll
    for (int mt=0;mt<4;mt++)
      #pragma unroll
      for (int g=0;g<4;g++) acc[mt][g] = (f32x4){0.f,0.f,0.f,0.f};
    for (int k8=0;k8<8;k8++){
      int k0 = k8*32;
      int gg = (k8 < 4) ? 2 : 3;
      int ncol = 16*w + l15;
      int koff = k0 + quad*8;
      bf16x8 bz = *reinterpret_cast<const bf16x8*>(&Wt[(ncol      )*256 + koff]);
      bf16x8 br = *reinterpret_cast<const bf16x8*>(&Wt[(ncol + 128)*256 + koff]);
      bf16x8 bc = *reinterpret_cast<const bf16x8*>(&Wt[(ncol + gg*128)*256 + koff]);
      #pragma unroll
      for (int mt=0;mt<4;mt++){
        bf16x8 a;
        if (k8 < 4) a = *reinterpret_cast<const bf16x8*>(&X[16*mt + l15][k0 + quad*8]);
        else        a = *reinterpret_cast<const bf16x8*>(&H1[16*mt + l15 + 8][k0 - 128 + quad*8]);
        acc[mt][0]  = __builtin_amdgcn_mfma_f32_16x16x32_bf16(a, bz, acc[mt][0], 0,0,0);
        acc[mt][1]  = __builtin_amdgcn_mfma_f32_16x16x32_bf16(a, br, acc[mt][1], 0,0,0);
        acc[mt][gg] = __builtin_amdgcn_mfma_f32_16x16x32_bf16(a, bc, acc[mt][gg], 0,0,0);
      }
    }
    __syncthreads();   // X is MFMA input above, epilogue output below
    int j = 16*w + l15;
    float bjz = bgru[j], bjr = bgru[128 + j], bjc = bgru[256 + j];
    #pragma unroll
    for (int mt=0;mt<4;mt++){
      #pragma unroll
      for (int reg=0;reg<4;reg++){
        int rl = 16*mt + quad*4 + reg;
        float z = fsig(acc[mt][0][reg] + bjz);
        float r = fsig(acc[mt][1][reg] + bjr);
        float cand = ftanh(acc[mt][2][reg] + bjc + r*acc[mt][3][reg]);
        float ho = bf2f(H1[rl + 8][j]);
        X[rl][j] = f2bf(z*ho + (1.f - z)*cand);
      }
    }
  }
  __syncthreads();
  for (int idx=tid; idx<64*16; idx+=512){
    int r = idx >> 4, c8 = idx & 15;
    *reinterpret_cast<bf16x8*>(&hout[(long)((b<<10) + n0 + r)*128 + c8*8]) =
        *reinterpret_cast<const bf16x8*>(&X[r][c8*8]);
  }
}

// Fused decoder + dest-attn + sparsemax + dual-vars, 1024 threads (r3 verbatim).
__global__ __launch_bounds__(1024,4) void k_decdas(const short* __restrict__ hn, const int* __restrict__ adj,
    const int* __restrict__ invadj, const short* __restrict__ Wpq, const float* __restrict__ b1,
    const float* __restrict__ W2, const float* __restrict__ b2_,
    const short* __restrict__ Wu1t, const float* __restrict__ bu1, const float* __restrict__ Wu2,
    const float* __restrict__ bu2_, float* __restrict__ norm_, float* __restrict__ dv){
  __shared__ short Hs[112][136];
  __shared__ short PQb[112][132];
  __shared__ short NSs[64][136];
  __shared__ int adjL[64][16];
  __shared__ float dvp[64][4];
  __shared__ float b1s[64], w2s[64], bu1s[64], wu2s[64];
  int tid = threadIdx.x;
  int blk = blockIdx.x;
  int b = blk >> 4;
  int n0 = (blk & 15) << 6;
  if (tid < 64){ b1s[tid] = b1[tid]; w2s[tid] = W2[tid]; bu1s[tid] = bu1[tid]; wu2s[tid] = Wu2[tid]; }
  for (int idx=tid; idx<112*16; idx+=1024){
    int r = idx >> 4, c8 = idx & 15;
    int g = (b << 10) + ((n0 - 24 + r) & 1023);
    *reinterpret_cast<bf16x8*>(&Hs[r][c8*8]) =
        *reinterpret_cast<const bf16x8*>(&hn[(long)g*128 + c8*8]);
  }
  {
    int r = tid >> 4, d = tid & 15;
    int a = adj[((b<<10) + n0 + r)*16 + d];
    adjL[r][d] = (a - n0 + 24) & 1023;
  }
  __syncthreads();
  int w = tid >> 6, lane = tid & 63;
  int l15 = lane & 15, quad = lane >> 4;
  int cw = w & 7, hw = w >> 3;
  // ---- PQ GEMM: 7 tiles; hw0 {0..3}, hw1 {4..6} ----
  {
    f32x4 acc[4];
    #pragma unroll
    for (int t=0;t<4;t++) acc[t] = (f32x4){0.f,0.f,0.f,0.f};
    #pragma unroll
    for (int kc=0;kc<4;kc++){
      int k0 = kc*32;
      bf16x8 bfr = *reinterpret_cast<const bf16x8*>(&Wpq[(16*cw + l15)*128 + k0 + quad*8]);
      #pragma unroll
      for (int t=0;t<4;t++){
        int mt = 4*hw + t;
        if (mt < 7){
          bf16x8 a = *reinterpret_cast<const bf16x8*>(&Hs[16*mt + l15][k0 + quad*8]);
          acc[t] = __builtin_amdgcn_mfma_f32_16x16x32_bf16(a, bfr, acc[t], 0,0,0);
        }
      }
    }
    int c = 16*cw + l15;
    #pragma unroll
    for (int t=0;t<4;t++){
      int mt = 4*hw + t;
      if (mt < 7){
        #pragma unroll
        for (int reg=0;reg<4;reg++)
          PQb[16*mt + quad*4 + reg][c] = f2bf(acc[t][reg]);
      }
    }
  }
  // ---- node_states gather: 1024 items, one per thread ----
  {
    int r = tid >> 4, c8 = tid & 15;
    float acc8[8] = {0,0,0,0,0,0,0,0};
    #pragma unroll 4
    for (int d=0; d<16; d++){
      bf16x8 hv = *reinterpret_cast<const bf16x8*>(&Hs[adjL[r][d]][c8*8]);
      #pragma unroll
      for (int q=0;q<8;q++) acc8[q] += bf2f(hv[q]);
    }
    bf16x8 sv;
    #pragma unroll
    for (int q=0;q<8;q++) sv[q] = f2bf(acc8[q]);
    *reinterpret_cast<bf16x8*>(&NSs[r][c8*8]) = sv;
  }
  __syncthreads();
  // ---- dual MLP MFMA on waves 0-7: col group c4 = w&3, row half h2 = w>>2 ----
  if (w < 8){
    int c4 = w & 3, h2 = w >> 2;
    f32x4 acc[2];
    #pragma unroll
    for (int t=0;t<2;t++) acc[t] = (f32x4){0.f,0.f,0.f,0.f};
    #pragma unroll
    for (int kc=0;kc<4;kc++){
      int k0 = kc*32;
      bf16x8 bfr = *reinterpret_cast<const bf16x8*>(&Wu1t[(16*c4 + l15)*128 + k0 + quad*8]);
      #pragma unroll
      for (int t=0;t<2;t++){
        bf16x8 a = *reinterpret_cast<const bf16x8*>(&NSs[16*(2*h2+t) + l15][k0 + quad*8]);
        acc[t] = __builtin_amdgcn_mfma_f32_16x16x32_bf16(a, bfr, acc[t], 0,0,0);
      }
    }
    int n = 16*c4 + l15;
    float bn = bu1s[n], wn = wu2s[n];
    #pragma unroll
    for (int t=0;t<2;t++){
      #pragma unroll
      for (int reg=0;reg<4;reg++){
        float p = ftanh(acc[t][reg] + bn) * wn;
        p += __shfl_xor(p, 1);
        p += __shfl_xor(p, 2);
        p += __shfl_xor(p, 4);
        p += __shfl_xor(p, 8);
        if (l15 == 0) dvp[16*(2*h2+t) + quad*4 + reg][c4] = p;
      }
    }
  }
  __syncthreads();
  float* nws = reinterpret_cast<float*>(&Hs[0][0]);   // [96][17]
  float b2v = b2_[0];
  for (int e = tid; e < 96*16; e += 1024){
    int rr = e >> 4, d = e & 15;
    int wnode = (n0 + rr - 16) & 1023;
    int wg = (b<<10) + wnode;
    int a = adj[wg*16 + d];
    int al = (a - n0 + 24) & 1023;
    int wl = rr + 8;
    float p = 0.f;
    #pragma unroll 8
    for (int c=0;c<64;c++)
      p += ftanh(bf2f(PQb[al][c]) + bf2f(PQb[wl][64 + c]) + b1s[c]) * w2s[c];
    nws[rr*17 + d] = p + b2v;
  }
  __syncthreads();
  if (tid < 64){
    float val = dvp[tid][0]+dvp[tid][1]+dvp[tid][2]+dvp[tid][3];
    dv[(b<<10) + n0 + tid] = fmaxf(val + bu2_[0], 0.f);
  }
  float* datt = reinterpret_cast<float*>(&PQb[0][0]); // [80][17]
  if (tid < 80){
    int wnode = (n0 + tid - 8) & 1023;
    int wg = (b<<10) + wnode;
    float vals[16];
    float m = -1e30f;
    #pragma unroll
    for (int d=0; d<16; d++){
      int iv = invadj[wg*16 + d];
      int il = (iv - n0 + 16) & 1023;
      vals[d] = nws[il*17 + d];
      m = fmaxf(m, vals[d]);
    }
    float s = 0.f;
    #pragma unroll
    for (int d=0; d<16; d++){ vals[d] = __expf(vals[d]-m); s += vals[d]; }
    float inv = frcp(s);
    #pragma unroll
    for (int d=0; d<16; d++) datt[tid*17 + d] = vals[d]*inv;
  }
  __syncthreads();
  if (tid < 64){
    int vg = (b<<10) + n0 + tid;
    float z[16], s[16];
    #pragma unroll
    for (int d=0; d<16; d++){
      int al = adjL[tid][d] - 16;
      z[d] = datt[al*17 + d];
      s[d] = z[d];
    }
    #pragma unroll
    for (int k2 = 2; k2 <= 16; k2 <<= 1){
      #pragma unroll
      for (int jj = k2 >> 1; jj > 0; jj >>= 1){
        #pragma unroll
        for (int i = 0; i < 16; i++){
          int l = i ^ jj;
          if (l > i){
            bool up = ((i & k2) == 0);
            float a = s[i], bb = s[l];
            bool sw = up ? (a > bb) : (a < bb);
            if (sw){ s[i]=bb; s[l]=a; }
          }
        }
      }
    }
    float cs = 0.f, zcs = 0.f; int kz = 1;
    #pragma unroll
    for (int j=0;j<16;j++){
      float zj = s[15-j];
      cs += zj;
      if (1.f + (float)(j+1)*zj > cs){ kz = j+1; zcs = cs; }
    }
    float tau = (zcs - 1.f)/(float)kz;
    #pragma unroll
    for (int d=0; d<16; d++) norm_[(long)vg*16 + d] = fmaxf(z[d]-tau, 0.f);
  }
}

// Flow solver, halo-redundant stencil form (r1 verbatim).
__global__ __launch_bounds__(256) void k_flowfin(const float* __restrict__ norm_,
    const float* __restrict__ dem, const int* __restrict__ invadj, const float* __restrict__ dv,
    float* __restrict__ out){
  __shared__ float nrmS[224*17];
  __shared__ float sbuf[2][224];
  __shared__ float red[4];
  int tid = threadIdx.x;
  int blk = blockIdx.x;
  int b = blk >> 4;
  int t0 = (blk & 15) << 6;
  for (int e=tid; e<224*4; e+=256){
    int r = e >> 2, q4 = e & 3;
    int v = (t0 - 80 + r) & 1023;
    float4 x = reinterpret_cast<const float4*>(&norm_[(long)((b<<10) + v)*16])[q4];
    nrmS[r*17 + q4*4+0] = x.x; nrmS[r*17 + q4*4+1] = x.y;
    nrmS[r*17 + q4*4+2] = x.z; nrmS[r*17 + q4*4+3] = x.w;
  }
  bool act = tid < 224;
  int r = tid;
  float dm = 0.f; int gv = 0;
  int ivl[16];
  if (act){
    int v = (t0 - 80 + r) & 1023;
    gv = (b<<10) + v;
    dm = dem[gv];
    #pragma unroll
    for (int d4=0; d4<4; d4++){
      int4 i4 = reinterpret_cast<const int4*>(&invadj[(long)gv*16])[d4];
      int t;
      t = (i4.x - t0 + 80) & 1023; ivl[d4*4+0] = t < 224 ? t : 223;
      t = (i4.y - t0 + 80) & 1023; ivl[d4*4+1] = t < 224 ? t : 223;
      t = (i4.z - t0 + 80) & 1023; ivl[d4*4+2] = t < 224 ? t : 223;
      t = (i4.w - t0 + 80) & 1023; ivl[d4*4+3] = t < 224 ? t : 223;
    }
    sbuf[0][r] = 0.f;
  }
  __syncthreads();
  float nrg[16];
  if (act){
    #pragma unroll
    for (int d=0; d<16; d++) nrg[d] = nrmS[ivl[d]*17 + d];
  }
  int p = 0;
  float s = 0.f;
  for (int it=0; it<10; it++){
    if (act){
      float inflow = 0.f;
      #pragma unroll
      for (int d=0; d<16; d++) inflow += nrg[d]*sbuf[p][ivl[d]];
      s = fmaxf(inflow - dm, 0.f);
      sbuf[1-p][r] = s;
    }
    p ^= 1;
    __syncthreads();
  }
  float partF = 0.f, partD = 0.f, partDD = 0.f;
  if (act && r >= 80 && r < 144){
    float nr2 = 0.f;
    #pragma unroll
    for (int d=0; d<16; d++){ float nv = nrmS[r*17 + d]; nr2 += nv*nv; }
    partF = nr2 * s * s;
    float dvv = dv[gv];
    float f = 0.f, vel = 0.f;
    #pragma unroll
    for (int it=0; it<10; it++){
      float g = 2.f*f + dvv;
      vel = 0.9f*vel - 0.01f*g;
      f = fmaxf(f + vel, 0.f);
    }
    partD = f*f + dvv*f;
    partDD = dvv * dm;
  }
  float val = partF - 16.f*partD + partDD;   // out[b] = sum F - (16*sum D - sum DD)
  #pragma unroll
  for (int off=32; off>0; off>>=1) val += __shfl_down(val, off);
  if ((tid & 63) == 0) red[tid>>6] = val;
  __syncthreads();
  if (tid == 0) atomicAdd(&out[b], red[0]+red[1]+red[2]+red[3]);
}

extern "C" void kernel_launch(void* const* d_in, const int* in_sizes, int n_in,
                              void* d_out, int out_size, void* d_ws, size_t ws_size,
                              hipStream_t stream){
  (void)in_sizes; (void)n_in; (void)out_size; (void)ws_size;
  const float* demands = (const float*)d_in[0];
  const float* nf      = (const float*)d_in[1];
  const float* emb     = (const float*)d_in[4];
  const float* Wenc    = (const float*)d_in[5];
  const float* benc    = (const float*)d_in[6];
  const float* Wgat    = (const float*)d_in[7];
  const float* bgat    = (const float*)d_in[8];
  const float* agat    = (const float*)d_in[9];
  const float* Wgx     = (const float*)d_in[10];
  const float* Wgh     = (const float*)d_in[11];
  const float* bgru    = (const float*)d_in[12];
  const float* Wd1     = (const float*)d_in[13];
  const float* bd1     = (const float*)d_in[14];
  const float* Wd2     = (const float*)d_in[15];
  const float* bd2     = (const float*)d_in[16];
  const float* Wu1     = (const float*)d_in[17];
  const float* bu1     = (const float*)d_in[18];
  const float* Wu2     = (const float*)d_in[19];
  const float* bu2     = (const float*)d_in[20];
  const int* adj       = (const int*)d_in[21];
  const int* invadj    = (const int*)d_in[22];

  float* ws    = (float*)d_ws;
  short* hnB   = (short*)(ws + OFF_HNB);
  float* nrm   = ws + OFF_NORM;
  float* dv    = ws + OFF_DV;
  short* wt    = (short*)(ws + OFF_WT);
  short* wtg   = (short*)(ws + OFF_WTG);
  short* wpq   = (short*)(ws + OFF_WPQ);
  short* wu1t  = (short*)(ws + OFF_WU1T);
  short* wenct = (short*)(ws + OFF_WENCT);

  k_pre<<<704, 256, 0, stream>>>(Wgx, Wgh, Wgat, Wd1, Wu1, Wenc, wt, wtg, wpq, wu1t, wenct,
                                 (float*)d_out);
  k_mega<<<BV/64, 512, 0, stream>>>(emb, nf, wenct, benc, adj, wtg, bgat, agat, wt, bgru, hnB);
  k_decdas<<<BV/64, 1024, 0, stream>>>(hnB, adj, invadj, wpq, bd1, Wd2, bd2,
                                       wu1t, bu1, Wu2, bu2, nrm, dv);
  k_flowfin<<<B*16, 256, 0, stream>>>(nrm, demands, invadj, dv, (float*)d_out);
}